// Round 1
// baseline (3327.506 us; speedup 1.0000x reference)
//
#include <hip/hip_runtime.h>
#include <cstdint>

// Problem constants (feature dims are fixed by the model; N/E/G derived from sizes)
#define FDIM 128
#define PCH 64

static inline int cdiv(long long a, long long b) { return (int)((a + b - 1) / b); }

// Ordered-uint encoding for float atomicMax (monotonic for all finite floats)
__device__ __forceinline__ unsigned fenc(float f) {
  unsigned b = __float_as_uint(f);
  return (b & 0x80000000u) ? ~b : (b | 0x80000000u);
}
__device__ __forceinline__ float fdec(unsigned u) {
  unsigned b = (u & 0x80000000u) ? (u & 0x7FFFFFFFu) : ~u;
  return __uint_as_float(b);
}

// ---------------- degree / norm ----------------
__global__ __launch_bounds__(256) void deg_kernel(const int* __restrict__ src,
                                                  const int* __restrict__ dst,
                                                  float* deg_in, float* deg_out, int E) {
  int i = blockIdx.x * 256 + threadIdx.x;
  if (i < E) {
    atomicAdd(&deg_in[dst[i]], 1.0f);
    atomicAdd(&deg_out[src[i]], 1.0f);
  }
}

__global__ __launch_bounds__(256) void dinv_kernel(float* d, int n2) {
  int i = blockIdx.x * 256 + threadIdx.x;
  if (i < n2) {
    float v = d[i];
    d[i] = v > 0.f ? 1.0f / sqrtf(v) : 0.f;  // matches where(deg>0, 1/sqrt(max(deg,1)), 0)
  }
}

__global__ __launch_bounds__(256) void cnt_kernel(const int* __restrict__ batch, float* cnt, int N) {
  int i = blockIdx.x * 256 + threadIdx.x;
  if (i < N) atomicAdd(&cnt[batch[i]], 1.0f);
}

// ---------------- fp32 matmul: out[N,128] = A[N,128] @ W[128,128] ----------------
// 64 rows x 64 cols per block (grid.y=2 col-blocks), 4x4 per thread.
// As stored XOR-swizzled so compute reads hit 4 distinct banks (no conflicts).
__global__ __launch_bounds__(256) void mm128(const float* __restrict__ A,
                                             const float* __restrict__ W,
                                             float* __restrict__ out, int nrows) {
  __shared__ float As[64][128];   // [r][k], swizzled columns
  __shared__ float Ws[128][64];   // [k][c]
  int r0 = blockIdx.x * 64;
  int cb = blockIdx.y * 64;
  int tid = threadIdx.x;

#pragma unroll
  for (int i = 0; i < 8; i++) {
    int v = tid + 256 * i;          // float4 index into 128x64 W tile
    int k = v >> 4, c4 = (v & 15) << 2;
    *(float4*)(&Ws[k][c4]) = *(const float4*)(W + k * FDIM + cb + c4);
  }
#pragma unroll
  for (int i = 0; i < 8; i++) {
    int v = tid + 256 * i;          // float4 index into 64x128 A tile
    int r = v >> 5, k4 = (v & 31) << 2;
    int row = r0 + r;
    float4 a;
    if (row < nrows) a = *(const float4*)(A + (size_t)row * FDIM + k4);
    else a = make_float4(0.f, 0.f, 0.f, 0.f);
    int swz = ((r >> 2) & 7) << 2;
    *(float4*)(&As[r][k4 ^ swz]) = a;
  }
  __syncthreads();

  int tx = tid & 15, ty = tid >> 4;
  int rbase = ty * 4;
  int swz = (ty & 7) << 2;
  float acc[4][4] = {};
#pragma unroll 8
  for (int k = 0; k < 128; k++) {
    int kx = k ^ swz;
    float a0 = As[rbase + 0][kx];
    float a1 = As[rbase + 1][kx];
    float a2 = As[rbase + 2][kx];
    float a3 = As[rbase + 3][kx];
    float4 w = *(float4*)(&Ws[k][tx * 4]);
    acc[0][0] += a0 * w.x; acc[0][1] += a0 * w.y; acc[0][2] += a0 * w.z; acc[0][3] += a0 * w.w;
    acc[1][0] += a1 * w.x; acc[1][1] += a1 * w.y; acc[1][2] += a1 * w.z; acc[1][3] += a1 * w.w;
    acc[2][0] += a2 * w.x; acc[2][1] += a2 * w.y; acc[2][2] += a2 * w.z; acc[2][3] += a2 * w.w;
    acc[3][0] += a3 * w.x; acc[3][1] += a3 * w.y; acc[3][2] += a3 * w.z; acc[3][3] += a3 * w.w;
  }
#pragma unroll
  for (int rr = 0; rr < 4; rr++) {
    int row = r0 + rbase + rr;
    if (row < nrows) {
      float4 o = make_float4(acc[rr][0], acc[rr][1], acc[rr][2], acc[rr][3]);
      *(float4*)(out + (size_t)row * FDIM + cb + tx * 4) = o;
    }
  }
}

// ---------------- GCN scatter (both directions, pre-scaled by alpha=0.5) ----------------
__global__ __launch_bounds__(256) void scatter_gcn(const float* __restrict__ tin,
                                                   const float* __restrict__ tout,
                                                   const int* __restrict__ src,
                                                   const int* __restrict__ dst,
                                                   const float* __restrict__ dinv_in,
                                                   const float* __restrict__ dinv_out,
                                                   float* __restrict__ acc, int E) {
  long long idx = (long long)blockIdx.x * 256 + threadIdx.x;
  if (idx >= (long long)E * FDIM) return;
  int e = (int)(idx >> 7), f = (int)(idx & 127);
  int s = src[e], d = dst[e];
  float nin  = 0.5f * dinv_in[s] * dinv_in[d];    // (1-alpha) * sym-norm (in-deg)
  float nout = 0.5f * dinv_out[s] * dinv_out[d];  // alpha * sym-norm (out-deg)
  atomicAdd(&acc[(size_t)d * FDIM + f], nin  * tin [(size_t)s * FDIM + f]);
  atomicAdd(&acc[(size_t)s * FDIM + f], nout * tout[(size_t)d * FDIM + f]);
}

__global__ __launch_bounds__(256) void finalize_relu(float* acc, const float* __restrict__ bin,
                                                     const float* __restrict__ bout, long long total) {
  long long i = (long long)blockIdx.x * 256 + threadIdx.x;
  if (i < total) {
    int f = (int)(i & 127);
    float v = acc[i] + 0.5f * bin[f] + 0.5f * bout[f];
    acc[i] = v > 0.f ? v : 0.f;
  }
}

// ---------------- GATv2 ----------------
// logits[e,h] = sum_c leaky( gl[s,h,c] + gr[d,h,c] + ea*we[h,c] ) * att[h,c]; atomicMax per (d,h)
__global__ __launch_bounds__(256) void gat_logits(const float* __restrict__ gl,
                                                  const float* __restrict__ gr,
                                                  const int* __restrict__ src,
                                                  const int* __restrict__ dst,
                                                  const float* __restrict__ eattr,
                                                  const float* __restrict__ we,
                                                  const float* __restrict__ att,
                                                  float* __restrict__ elog,
                                                  unsigned* __restrict__ menc,
                                                  int E, int N) {
  __shared__ float swe[128], satt[128];
  int t = threadIdx.x;
  if (t < 128) { swe[t] = we[t]; satt[t] = att[t]; }
  __syncthreads();
  int tot = (E + N) * 4;
  int idx = blockIdx.x * 256 + t;
  if (idx >= tot) return;
  int e = idx >> 2, h = idx & 3;
  int s, d; float ea;
  if (e < E) { s = src[e]; d = dst[e]; ea = eattr[e]; }
  else { s = e - E; d = s; ea = 1.0f; }
  const float4* glp = (const float4*)(gl + (size_t)s * FDIM + h * 32);
  const float4* grp = (const float4*)(gr + (size_t)d * FDIM + h * 32);
  float acc = 0.f;
#pragma unroll
  for (int q = 0; q < 8; q++) {
    float4 a = glp[q], b = grp[q];
    const float* wp = &swe[h * 32 + q * 4];
    const float* ap = &satt[h * 32 + q * 4];
    float v;
    v = a.x + b.x + ea * wp[0]; v = v > 0.f ? v : 0.2f * v; acc += v * ap[0];
    v = a.y + b.y + ea * wp[1]; v = v > 0.f ? v : 0.2f * v; acc += v * ap[1];
    v = a.z + b.z + ea * wp[2]; v = v > 0.f ? v : 0.2f * v; acc += v * ap[2];
    v = a.w + b.w + ea * wp[3]; v = v > 0.f ? v : 0.2f * v; acc += v * ap[3];
  }
  elog[idx] = acc;
  atomicMax(&menc[(size_t)d * 4 + h], fenc(acc));
}

__global__ __launch_bounds__(256) void ex_kernel(float* __restrict__ elog,
                                                 const unsigned* __restrict__ menc,
                                                 const int* __restrict__ dst,
                                                 float* __restrict__ denom, int E, int N) {
  int tot = (E + N) * 4;
  int idx = blockIdx.x * 256 + threadIdx.x;
  if (idx >= tot) return;
  int e = idx >> 2, h = idx & 3;
  int d = e < E ? dst[e] : e - E;
  float m = fdec(menc[(size_t)d * 4 + h]);
  float ex = expf(elog[idx] - m);
  elog[idx] = ex;
  atomicAdd(&denom[(size_t)d * 4 + h], ex);
}

__global__ __launch_bounds__(256) void attw_kernel(float* __restrict__ elog,
                                                   const float* __restrict__ denom,
                                                   const int* __restrict__ dst, int E, int N) {
  int tot = (E + N) * 4;
  int idx = blockIdx.x * 256 + threadIdx.x;
  if (idx >= tot) return;
  int e = idx >> 2, h = idx & 3;
  int d = e < E ? dst[e] : e - E;
  elog[idx] = elog[idx] / denom[(size_t)d * 4 + h];
}

__global__ __launch_bounds__(256) void out2_scatter(const float* __restrict__ gl,
                                                    const float* __restrict__ attw,
                                                    const int* __restrict__ src,
                                                    const int* __restrict__ dst,
                                                    float* __restrict__ out2, int E, int N) {
  long long idx = (long long)blockIdx.x * 256 + threadIdx.x;
  long long tot = (long long)(E + N) * FDIM;
  if (idx >= tot) return;
  int e = (int)(idx >> 7), f = (int)(idx & 127);
  int s, d;
  if (e < E) { s = src[e]; d = dst[e]; } else { s = e - E; d = s; }
  float a = attw[(size_t)e * 4 + (f >> 5)];
  atomicAdd(&out2[(size_t)d * FDIM + f], a * gl[(size_t)s * FDIM + f]);
}

// ---------------- mean pool (batch is sorted: running-sum per contiguous chunk) ----------------
__global__ __launch_bounds__(128) void pool_kernel(const float* __restrict__ srcf,
                                                   const int* __restrict__ batch,
                                                   const float* __restrict__ bias,
                                                   float* __restrict__ zb,
                                                   int colOff, int N) {
  __shared__ int sb[PCH];
  int c0 = blockIdx.x * PCH;
  int t = threadIdx.x;
  int nmax = N - c0; if (nmax > PCH) nmax = PCH;
  if (t < nmax) sb[t] = batch[c0 + t];
  __syncthreads();
  float b = bias ? bias[t] : 0.0f;
  float run = 0.f;
  int gp = sb[0];
  for (int i = 0; i < nmax; i++) {
    int g = sb[i];
    if (g != gp) {
      atomicAdd(&zb[(size_t)gp * 256 + colOff + t], run);
      run = 0.f; gp = g;
    }
    run += srcf[(size_t)(c0 + i) * FDIM + t] + b;
  }
  atomicAdd(&zb[(size_t)gp * 256 + colOff + t], run);
}

// ---------------- head: z=concat(x1,x2); relu(z@w1+b1)@w2+b2 ----------------
__global__ __launch_bounds__(128) void head_kernel(const float* __restrict__ zb,
                                                   const float* __restrict__ cnt,
                                                   const float* __restrict__ w1,
                                                   const float* __restrict__ b1,
                                                   const float* __restrict__ w2,
                                                   const float* __restrict__ b2,
                                                   float* __restrict__ out, int G) {
  __shared__ float z[256];
  __shared__ float y[128];
  int g = blockIdx.x, t = threadIdx.x;
  float c = cnt[g];
  float cm = c > 1.f ? c : 1.f;
  z[t]       = zb[(size_t)g * 256 + t] / cm;
  z[t + 128] = zb[(size_t)g * 256 + 128 + t] / cm;
  __syncthreads();
  float acc = b1[t];
  for (int k = 0; k < 256; k++) acc += z[k] * w1[k * 128 + t];
  y[t] = acc > 0.f ? acc : 0.f;
  __syncthreads();
  if (t < 2) {
    float o = b2[t];
    for (int j = 0; j < 128; j++) o += y[j] * w2[j * 2 + t];
    out[(size_t)g * 2 + t] = o;
  }
}

extern "C" void kernel_launch(void* const* d_in, const int* in_sizes, int n_in,
                              void* d_out, int out_size, void* d_ws, size_t ws_size,
                              hipStream_t stream) {
  const float* x     = (const float*)d_in[0];
  const int*   ei    = (const int*)d_in[1];
  const float* eattr = (const float*)d_in[2];
  const int*   batch = (const int*)d_in[3];
  const float* dwi   = (const float*)d_in[4];
  const float* dbi   = (const float*)d_in[5];
  const float* dwo   = (const float*)d_in[6];
  const float* dbo   = (const float*)d_in[7];
  const float* wl    = (const float*)d_in[8];
  const float* wr    = (const float*)d_in[9];
  const float* we    = (const float*)d_in[10];
  const float* att   = (const float*)d_in[11];
  const float* gatb  = (const float*)d_in[12];
  const float* w1    = (const float*)d_in[13];
  const float* b1    = (const float*)d_in[14];
  const float* w2    = (const float*)d_in[15];
  const float* b2    = (const float*)d_in[16];

  int N = in_sizes[0] / FDIM;
  int E = in_sizes[1] / 2;
  int G = out_size / 2;
  const int* src = ei;
  const int* dst = ei + E;

  // workspace layout (fp32 elements); total ~176 MB
  float* ws = (float*)d_ws;
  size_t off = 0;
  float* A     = ws + off; off += (size_t)N * FDIM;   // h / acc / out2
  float* B     = ws + off; off += (size_t)N * FDIM;   // t_in / gl
  float* C     = ws + off; off += (size_t)N * FDIM;   // t_out / gr
  float* dinv  = ws + off; off += 2 * (size_t)N;      // [deg_in|deg_out] -> dinv in-place
  float* elog  = ws + off; off += (size_t)(E + N) * 4; // logits -> ex -> att weights
  unsigned* menc = (unsigned*)(ws + off); off += (size_t)N * 4;
  float* denom = ws + off; off += (size_t)N * 4;      // contiguous after menc (joint memset)
  float* zb    = ws + off; off += (size_t)G * 256;    // pooled sums [x1|x2]
  float* cnt   = ws + off; off += (size_t)G;          // contiguous after zb (joint memset)

  size_t nf = (size_t)N * FDIM;
  dim3 mmg(cdiv(N, 64), 2);

  // degrees / norms (edges fixed but recomputed every call — ws is re-poisoned)
  hipMemsetAsync(dinv, 0, 2 * (size_t)N * sizeof(float), stream);
  deg_kernel<<<cdiv(E, 256), 256, 0, stream>>>(src, dst, dinv, dinv + N, E);
  dinv_kernel<<<cdiv(2 * (long long)N, 256), 256, 0, stream>>>(dinv, 2 * N);

  // pool counts + pooled-sum buffer
  hipMemsetAsync(zb, 0, ((size_t)G * 256 + G) * sizeof(float), stream);
  cnt_kernel<<<cdiv(N, 256), 256, 0, stream>>>(batch, cnt, N);

  // ---- DirGNN layer 0 (h = x) ----
  mm128<<<mmg, 256, 0, stream>>>(x, dwi, B, N);
  mm128<<<mmg, 256, 0, stream>>>(x, dwo, C, N);
  hipMemsetAsync(A, 0, nf * sizeof(float), stream);
  scatter_gcn<<<cdiv((long long)E * FDIM, 256), 256, 0, stream>>>(B, C, src, dst, dinv, dinv + N, A, E);
  finalize_relu<<<cdiv((long long)nf, 256), 256, 0, stream>>>(A, dbi, dbo, (long long)nf);

  // ---- DirGNN layer 1 (h = A) ----
  mm128<<<mmg, 256, 0, stream>>>(A, dwi + 16384, B, N);
  mm128<<<mmg, 256, 0, stream>>>(A, dwo + 16384, C, N);
  hipMemsetAsync(A, 0, nf * sizeof(float), stream);
  scatter_gcn<<<cdiv((long long)E * FDIM, 256), 256, 0, stream>>>(B, C, src, dst, dinv, dinv + N, A, E);
  finalize_relu<<<cdiv((long long)nf, 256), 256, 0, stream>>>(A, dbi + 128, dbo + 128, (long long)nf);

  // pool x1 -> zb[:, 0:128]
  pool_kernel<<<cdiv(N, PCH), 128, 0, stream>>>(A, batch, nullptr, zb, 0, N);

  // ---- GATv2 branch (on original x) ----
  mm128<<<mmg, 256, 0, stream>>>(x, wl, B, N);  // gl (source transform)
  mm128<<<mmg, 256, 0, stream>>>(x, wr, C, N);  // gr (target transform)
  hipMemsetAsync(menc, 0, (size_t)N * 4 * sizeof(unsigned) * 2, stream);  // menc + denom
  int tot4 = (E + N) * 4;
  gat_logits<<<cdiv(tot4, 256), 256, 0, stream>>>(B, C, src, dst, eattr, we, att, elog, menc, E, N);
  ex_kernel<<<cdiv(tot4, 256), 256, 0, stream>>>(elog, menc, dst, denom, E, N);
  attw_kernel<<<cdiv(tot4, 256), 256, 0, stream>>>(elog, denom, dst, E, N);
  hipMemsetAsync(A, 0, nf * sizeof(float), stream);
  out2_scatter<<<cdiv((long long)(E + N) * FDIM, 256), 256, 0, stream>>>(B, elog, src, dst, A, E, N);

  // pool x2 -> zb[:, 128:256] (gat_b folded in per-node; exact when cnt>0, zero otherwise)
  pool_kernel<<<cdiv(N, PCH), 128, 0, stream>>>(A, batch, gatb, zb, 128, N);

  // head
  head_kernel<<<G, 128, 0, stream>>>(zb, cnt, w1, b1, w2, b2, (float*)d_out, G);
}

// Round 2
// 1715.315 us; speedup vs baseline: 1.9399x; 1.9399x over previous
//
#include <hip/hip_runtime.h>
#include <cstdint>

#define FDIM 128
#define PCH 64

static inline int cdiv(long long a, long long b) { return (int)((a + b - 1) / b); }

// ---------------- degree histograms (int) ----------------
__global__ __launch_bounds__(256) void degi_kernel(const int* __restrict__ src,
                                                   const int* __restrict__ dst,
                                                   int* deg_in, int* deg_out, int E) {
  int i = blockIdx.x * 256 + threadIdx.x;
  if (i < E) {
    atomicAdd(&deg_in[dst[i]], 1);
    atomicAdd(&deg_out[src[i]], 1);
  }
}

// dinv[i] = deg>0 ? 1/sqrt(deg) : 0   (matches where(deg>0, 1/sqrt(max(deg,1)), 0))
__global__ __launch_bounds__(256) void dinv2_kernel(const int* __restrict__ degs,
                                                    float* __restrict__ dinv, int n2) {
  int i = blockIdx.x * 256 + threadIdx.x;
  if (i < n2) {
    int v = degs[i];
    dinv[i] = v > 0 ? 1.0f / sqrtf((float)v) : 0.f;
  }
}

__global__ __launch_bounds__(256) void cnt_kernel(const int* __restrict__ batch, float* cnt, int N) {
  int i = blockIdx.x * 256 + threadIdx.x;
  if (i < N) atomicAdd(&cnt[batch[i]], 1.0f);
}

// ---------------- hierarchical exclusive scan (n <= 256*1024) ----------------
// scan1: each 256-thread block scans 1024 elements (4/thread), writes block-local
// exclusive scan + per-block total.
__global__ __launch_bounds__(256) void scan1(const int* __restrict__ in, int* __restrict__ out,
                                             int* __restrict__ bsums, int n) {
  __shared__ int tmp[256];
  int t = threadIdx.x;
  int base = blockIdx.x * 1024 + t * 4;
  int a[4];
#pragma unroll
  for (int j = 0; j < 4; j++) a[j] = (base + j < n) ? in[base + j] : 0;
  int s = a[0] + a[1] + a[2] + a[3];
  tmp[t] = s;
  __syncthreads();
  for (int off = 1; off < 256; off <<= 1) {
    int v = (t >= off) ? tmp[t - off] : 0;
    __syncthreads();
    tmp[t] += v;
    __syncthreads();
  }
  int excl = tmp[t] - s;
  int run = excl;
#pragma unroll
  for (int j = 0; j < 4; j++) {
    if (base + j < n) out[base + j] = run;
    run += a[j];
  }
  if (t == 255) bsums[blockIdx.x] = tmp[255];
}

// scan2: single block scans up to 256 block sums -> exclusive offsets
__global__ __launch_bounds__(256) void scan2(const int* __restrict__ bsums,
                                             int* __restrict__ boff, int nb) {
  __shared__ int tmp[256];
  int t = threadIdx.x;
  int s = (t < nb) ? bsums[t] : 0;
  tmp[t] = s;
  __syncthreads();
  for (int off = 1; off < 256; off <<= 1) {
    int v = (t >= off) ? tmp[t - off] : 0;
    __syncthreads();
    tmp[t] += v;
    __syncthreads();
  }
  if (t < nb) boff[t] = tmp[t] - s;
}

// scan3: add block offsets; also initialize the fill cursors
__global__ __launch_bounds__(256) void scan3(int* __restrict__ out, const int* __restrict__ boff,
                                             int* __restrict__ cur, int n) {
  int i = blockIdx.x * 256 + threadIdx.x;
  if (i < n) {
    int v = out[i] + boff[i >> 10];
    out[i] = v;
    cur[i] = v;
  }
}

// ---------------- CSR fill ----------------
__global__ __launch_bounds__(256) void fill_kernel(const int* __restrict__ src,
                                                   const int* __restrict__ dst,
                                                   int* cur_in, int* cur_out,
                                                   int* __restrict__ csr_in_src,
                                                   int* __restrict__ csr_in_eid,
                                                   int* __restrict__ csr_out_dst, int E) {
  int i = blockIdx.x * 256 + threadIdx.x;
  if (i < E) {
    int s = src[i], d = dst[i];
    int p = atomicAdd(&cur_in[d], 1);
    csr_in_src[p] = s;
    csr_in_eid[p] = i;
    int q = atomicAdd(&cur_out[s], 1);
    csr_out_dst[q] = d;
  }
}

// ---------------- fp32 matmul: out[N,128] = A[N,128] @ W[128,128] ----------------
__global__ __launch_bounds__(256) void mm128(const float* __restrict__ A,
                                             const float* __restrict__ W,
                                             float* __restrict__ out, int nrows) {
  __shared__ float As[64][128];
  __shared__ float Ws[128][64];
  int r0 = blockIdx.x * 64;
  int cb = blockIdx.y * 64;
  int tid = threadIdx.x;

#pragma unroll
  for (int i = 0; i < 8; i++) {
    int v = tid + 256 * i;
    int k = v >> 4, c4 = (v & 15) << 2;
    *(float4*)(&Ws[k][c4]) = *(const float4*)(W + k * FDIM + cb + c4);
  }
#pragma unroll
  for (int i = 0; i < 8; i++) {
    int v = tid + 256 * i;
    int r = v >> 5, k4 = (v & 31) << 2;
    int row = r0 + r;
    float4 a;
    if (row < nrows) a = *(const float4*)(A + (size_t)row * FDIM + k4);
    else a = make_float4(0.f, 0.f, 0.f, 0.f);
    int swz = ((r >> 2) & 7) << 2;
    *(float4*)(&As[r][k4 ^ swz]) = a;
  }
  __syncthreads();

  int tx = tid & 15, ty = tid >> 4;
  int rbase = ty * 4;
  int swz = (ty & 7) << 2;
  float acc[4][4] = {};
#pragma unroll 8
  for (int k = 0; k < 128; k++) {
    int kx = k ^ swz;
    float a0 = As[rbase + 0][kx];
    float a1 = As[rbase + 1][kx];
    float a2 = As[rbase + 2][kx];
    float a3 = As[rbase + 3][kx];
    float4 w = *(float4*)(&Ws[k][tx * 4]);
    acc[0][0] += a0 * w.x; acc[0][1] += a0 * w.y; acc[0][2] += a0 * w.z; acc[0][3] += a0 * w.w;
    acc[1][0] += a1 * w.x; acc[1][1] += a1 * w.y; acc[1][2] += a1 * w.z; acc[1][3] += a1 * w.w;
    acc[2][0] += a2 * w.x; acc[2][1] += a2 * w.y; acc[2][2] += a2 * w.z; acc[2][3] += a2 * w.w;
    acc[3][0] += a3 * w.x; acc[3][1] += a3 * w.y; acc[3][2] += a3 * w.z; acc[3][3] += a3 * w.w;
  }
#pragma unroll
  for (int rr = 0; rr < 4; rr++) {
    int row = r0 + rbase + rr;
    if (row < nrows) {
      float4 o = make_float4(acc[rr][0], acc[rr][1], acc[rr][2], acc[rr][3]);
      *(float4*)(out + (size_t)row * FDIM + cb + tx * 4) = o;
    }
  }
}

// ---------------- GCN aggregation: gather form, fused bias+relu ----------------
// one 128-thread block per node; no atomics, coalesced writes.
__global__ __launch_bounds__(128) void gcn_gather(const float* __restrict__ tin,
                                                  const float* __restrict__ tout,
                                                  const int* __restrict__ rp_in,
                                                  const int* __restrict__ deg_in,
                                                  const int* __restrict__ adj_in,
                                                  const int* __restrict__ rp_out,
                                                  const int* __restrict__ deg_out,
                                                  const int* __restrict__ adj_out,
                                                  const float* __restrict__ dinv_in,
                                                  const float* __restrict__ dinv_out,
                                                  const float* __restrict__ bin,
                                                  const float* __restrict__ bout,
                                                  float* __restrict__ outp) {
  int d = blockIdx.x, t = threadIdx.x;
  float di = dinv_in[d], dq = dinv_out[d];
  float acc = 0.f;
  int p = rp_in[d], n1 = deg_in[d];
  for (int k = 0; k < n1; k++) {
    int s = adj_in[p + k];
    acc += (0.5f * di * dinv_in[s]) * tin[(size_t)s * FDIM + t];
  }
  int q = rp_out[d], n2 = deg_out[d];
  for (int k = 0; k < n2; k++) {
    int s = adj_out[q + k];
    acc += (0.5f * dq * dinv_out[s]) * tout[(size_t)s * FDIM + t];
  }
  float v = acc + 0.5f * (bin[t] + bout[t]);
  outp[(size_t)d * FDIM + t] = v > 0.f ? v : 0.f;
}

// ---------------- GATv2: fused online-softmax gather ----------------
// one 128-thread block per node d; iterates incoming edges + self loop once,
// flash-style running (m, denom, o). No atomics, no elog buffer.
__global__ __launch_bounds__(128) void gat_fused(const float* __restrict__ gl,
                                                 const float* __restrict__ gr,
                                                 const int* __restrict__ rp,
                                                 const int* __restrict__ deg,
                                                 const int* __restrict__ adj_src,
                                                 const int* __restrict__ adj_eid,
                                                 const float* __restrict__ eattr,
                                                 const float* __restrict__ we,
                                                 const float* __restrict__ att,
                                                 const float* __restrict__ gatb,
                                                 float* __restrict__ outp) {
  int d = blockIdx.x, t = threadIdx.x;
  float grv = gr[(size_t)d * FDIM + t];
  float wev = we[t], attv = att[t];
  int p = rp[d], n1 = deg[d];
  float m = -1e30f, denom = 0.f, oacc = 0.f;
  for (int k = 0; k <= n1; k++) {
    int s; float ea;
    if (k < n1) { int idx = p + k; s = adj_src[idx]; ea = eattr[adj_eid[idx]]; }
    else { s = d; ea = 1.0f; }
    float glv = gl[(size_t)s * FDIM + t];
    float v = glv + grv + ea * wev;
    v = v > 0.f ? v : 0.2f * v;           // leaky_relu, slope 0.2
    float pv = v * attv;                   // einsum over c within the head
    pv += __shfl_xor(pv, 16, 32);
    pv += __shfl_xor(pv, 8, 32);
    pv += __shfl_xor(pv, 4, 32);
    pv += __shfl_xor(pv, 2, 32);
    pv += __shfl_xor(pv, 1, 32);           // pv = logit for this head, broadcast
    float mn = fmaxf(m, pv);
    float sc = expf(m - mn);
    float w = expf(pv - mn);
    denom = denom * sc + w;
    oacc = oacc * sc + w * glv;
    m = mn;
  }
  outp[(size_t)d * FDIM + t] = oacc / denom + gatb[t];
}

// ---------------- mean pool (batch sorted: running-sum per contiguous chunk) ----------------
__global__ __launch_bounds__(128) void pool_kernel(const float* __restrict__ srcf,
                                                   const int* __restrict__ batch,
                                                   float* __restrict__ zb,
                                                   int colOff, int N) {
  __shared__ int sb[PCH];
  int c0 = blockIdx.x * PCH;
  int t = threadIdx.x;
  int nmax = N - c0; if (nmax > PCH) nmax = PCH;
  if (t < nmax) sb[t] = batch[c0 + t];
  __syncthreads();
  float run = 0.f;
  int gp = sb[0];
  for (int i = 0; i < nmax; i++) {
    int g = sb[i];
    if (g != gp) {
      atomicAdd(&zb[(size_t)gp * 256 + colOff + t], run);
      run = 0.f; gp = g;
    }
    run += srcf[(size_t)(c0 + i) * FDIM + t];
  }
  atomicAdd(&zb[(size_t)gp * 256 + colOff + t], run);
}

// ---------------- head ----------------
__global__ __launch_bounds__(128) void head_kernel(const float* __restrict__ zb,
                                                   const float* __restrict__ cnt,
                                                   const float* __restrict__ w1,
                                                   const float* __restrict__ b1,
                                                   const float* __restrict__ w2,
                                                   const float* __restrict__ b2,
                                                   float* __restrict__ out, int G) {
  __shared__ float z[256];
  __shared__ float y[128];
  int g = blockIdx.x, t = threadIdx.x;
  float c = cnt[g];
  float cm = c > 1.f ? c : 1.f;
  z[t]       = zb[(size_t)g * 256 + t] / cm;
  z[t + 128] = zb[(size_t)g * 256 + 128 + t] / cm;
  __syncthreads();
  float acc = b1[t];
  for (int k = 0; k < 256; k++) acc += z[k] * w1[k * 128 + t];
  y[t] = acc > 0.f ? acc : 0.f;
  __syncthreads();
  if (t < 2) {
    float o = b2[t];
    for (int j = 0; j < 128; j++) o += y[j] * w2[j * 2 + t];
    out[(size_t)g * 2 + t] = o;
  }
}

extern "C" void kernel_launch(void* const* d_in, const int* in_sizes, int n_in,
                              void* d_out, int out_size, void* d_ws, size_t ws_size,
                              hipStream_t stream) {
  const float* x     = (const float*)d_in[0];
  const int*   ei    = (const int*)d_in[1];
  const float* eattr = (const float*)d_in[2];
  const int*   batch = (const int*)d_in[3];
  const float* dwi   = (const float*)d_in[4];
  const float* dbi   = (const float*)d_in[5];
  const float* dwo   = (const float*)d_in[6];
  const float* dbo   = (const float*)d_in[7];
  const float* wl    = (const float*)d_in[8];
  const float* wr    = (const float*)d_in[9];
  const float* we    = (const float*)d_in[10];
  const float* att   = (const float*)d_in[11];
  const float* gatb  = (const float*)d_in[12];
  const float* w1    = (const float*)d_in[13];
  const float* b1    = (const float*)d_in[14];
  const float* w2    = (const float*)d_in[15];
  const float* b2    = (const float*)d_in[16];

  int N = in_sizes[0] / FDIM;
  int E = in_sizes[1] / 2;
  int G = out_size / 2;
  const int* src = ei;
  const int* dst = ei + E;

  // ---- workspace layout (4-byte elements), ~170 MB ----
  float* ws = (float*)d_ws;
  size_t off = 0;
  float* A        = ws + off; off += (size_t)N * FDIM;
  float* B        = ws + off; off += (size_t)N * FDIM;
  float* C        = ws + off; off += (size_t)N * FDIM;
  float* dinv2    = ws + off; off += 2 * (size_t)N;      // [dinv_in | dinv_out]
  int* deg2       = (int*)(ws + off); off += 2 * (size_t)N;  // [deg_in | deg_out]
  int* rp_in      = (int*)(ws + off); off += (size_t)N;
  int* rp_out     = (int*)(ws + off); off += (size_t)N;
  int* cur_in     = (int*)(ws + off); off += (size_t)N;
  int* cur_out    = (int*)(ws + off); off += (size_t)N;
  int* csr_in_src = (int*)(ws + off); off += (size_t)E;
  int* csr_in_eid = (int*)(ws + off); off += (size_t)E;
  int* csr_out_dst= (int*)(ws + off); off += (size_t)E;
  int* bsums      = (int*)(ws + off); off += 256;
  int* boff       = (int*)(ws + off); off += 256;
  float* zb       = ws + off; off += (size_t)G * 256;
  float* cnt      = ws + off; off += (size_t)G;

  int* deg_in = deg2, *deg_out = deg2 + N;
  float* dinv_in = dinv2, *dinv_out = dinv2 + N;

  dim3 mmg(cdiv(N, 64), 2);
  int nb1 = cdiv(N, 1024);  // scan1 blocks (<=256 for N<=262144)

  // ---- CSR build ----
  hipMemsetAsync(deg2, 0, 2 * (size_t)N * sizeof(int), stream);
  degi_kernel<<<cdiv(E, 256), 256, 0, stream>>>(src, dst, deg_in, deg_out, E);
  dinv2_kernel<<<cdiv(2LL * N, 256), 256, 0, stream>>>(deg2, dinv2, 2 * N);
  scan1<<<nb1, 256, 0, stream>>>(deg_in, rp_in, bsums, N);
  scan2<<<1, 256, 0, stream>>>(bsums, boff, nb1);
  scan3<<<cdiv(N, 256), 256, 0, stream>>>(rp_in, boff, cur_in, N);
  scan1<<<nb1, 256, 0, stream>>>(deg_out, rp_out, bsums, N);
  scan2<<<1, 256, 0, stream>>>(bsums, boff, nb1);
  scan3<<<cdiv(N, 256), 256, 0, stream>>>(rp_out, boff, cur_out, N);
  fill_kernel<<<cdiv(E, 256), 256, 0, stream>>>(src, dst, cur_in, cur_out,
                                                csr_in_src, csr_in_eid, csr_out_dst, E);

  // ---- pool counts ----
  hipMemsetAsync(zb, 0, ((size_t)G * 256 + G) * sizeof(float), stream);
  cnt_kernel<<<cdiv(N, 256), 256, 0, stream>>>(batch, cnt, N);

  // ---- DirGNN layer 0 (h = x) ----
  mm128<<<mmg, 256, 0, stream>>>(x, dwi, B, N);
  mm128<<<mmg, 256, 0, stream>>>(x, dwo, C, N);
  gcn_gather<<<N, 128, 0, stream>>>(B, C, rp_in, deg_in, csr_in_src,
                                    rp_out, deg_out, csr_out_dst,
                                    dinv_in, dinv_out, dbi, dbo, A);
  // ---- DirGNN layer 1 (h = A) ----
  mm128<<<mmg, 256, 0, stream>>>(A, dwi + 16384, B, N);
  mm128<<<mmg, 256, 0, stream>>>(A, dwo + 16384, C, N);
  gcn_gather<<<N, 128, 0, stream>>>(B, C, rp_in, deg_in, csr_in_src,
                                    rp_out, deg_out, csr_out_dst,
                                    dinv_in, dinv_out, dbi + 128, dbo + 128, A);
  // pool x1 -> zb[:, 0:128]
  pool_kernel<<<cdiv(N, PCH), 128, 0, stream>>>(A, batch, zb, 0, N);

  // ---- GATv2 branch (on original x) ----
  mm128<<<mmg, 256, 0, stream>>>(x, wl, B, N);   // gl (source transform)
  mm128<<<mmg, 256, 0, stream>>>(x, wr, C, N);   // gr (target transform)
  gat_fused<<<N, 128, 0, stream>>>(B, C, rp_in, deg_in, csr_in_src, csr_in_eid,
                                   eattr, we, att, gatb, A);
  // pool x2 -> zb[:, 128:256]
  pool_kernel<<<cdiv(N, PCH), 128, 0, stream>>>(A, batch, zb, 128, N);

  // head
  head_kernel<<<G, 128, 0, stream>>>(zb, cnt, w1, b1, w2, b2, (float*)d_out, G);
}

// Round 3
// 1676.116 us; speedup vs baseline: 1.9852x; 1.0234x over previous
//
#include <hip/hip_runtime.h>
#include <cstdint>

#define FDIM 128
#define PCH 64

static inline int cdiv(long long a, long long b) { return (int)((a + b - 1) / b); }

// ---------------- degree histograms (int) ----------------
__global__ __launch_bounds__(256) void degi_kernel(const int* __restrict__ src,
                                                   const int* __restrict__ dst,
                                                   int* deg_in, int* deg_out, int E) {
  int i = blockIdx.x * 256 + threadIdx.x;
  if (i < E) {
    atomicAdd(&deg_in[dst[i]], 1);
    atomicAdd(&deg_out[src[i]], 1);
  }
}

// dinv[i] = deg>0 ? 1/sqrt(deg) : 0
__global__ __launch_bounds__(256) void dinv2_kernel(const int* __restrict__ degs,
                                                    float* __restrict__ dinv, int n2) {
  int i = blockIdx.x * 256 + threadIdx.x;
  if (i < n2) {
    int v = degs[i];
    dinv[i] = v > 0 ? 1.0f / sqrtf((float)v) : 0.f;
  }
}

__global__ __launch_bounds__(256) void cnt_kernel(const int* __restrict__ batch, float* cnt, int N) {
  int i = blockIdx.x * 256 + threadIdx.x;
  if (i < N) atomicAdd(&cnt[batch[i]], 1.0f);
}

// ---------------- hierarchical exclusive scan (n <= 256*1024) ----------------
__global__ __launch_bounds__(256) void scan1(const int* __restrict__ in, int* __restrict__ out,
                                             int* __restrict__ bsums, int n) {
  __shared__ int tmp[256];
  int t = threadIdx.x;
  int base = blockIdx.x * 1024 + t * 4;
  int a[4];
#pragma unroll
  for (int j = 0; j < 4; j++) a[j] = (base + j < n) ? in[base + j] : 0;
  int s = a[0] + a[1] + a[2] + a[3];
  tmp[t] = s;
  __syncthreads();
  for (int off = 1; off < 256; off <<= 1) {
    int v = (t >= off) ? tmp[t - off] : 0;
    __syncthreads();
    tmp[t] += v;
    __syncthreads();
  }
  int excl = tmp[t] - s;
  int run = excl;
#pragma unroll
  for (int j = 0; j < 4; j++) {
    if (base + j < n) out[base + j] = run;
    run += a[j];
  }
  if (t == 255) bsums[blockIdx.x] = tmp[255];
}

__global__ __launch_bounds__(256) void scan2(const int* __restrict__ bsums,
                                             int* __restrict__ boff, int nb) {
  __shared__ int tmp[256];
  int t = threadIdx.x;
  int s = (t < nb) ? bsums[t] : 0;
  tmp[t] = s;
  __syncthreads();
  for (int off = 1; off < 256; off <<= 1) {
    int v = (t >= off) ? tmp[t - off] : 0;
    __syncthreads();
    tmp[t] += v;
    __syncthreads();
  }
  if (t < nb) boff[t] = tmp[t] - s;
}

__global__ __launch_bounds__(256) void scan3(int* __restrict__ out, const int* __restrict__ boff,
                                             int* __restrict__ cur, int n) {
  int i = blockIdx.x * 256 + threadIdx.x;
  if (i < n) {
    int v = out[i] + boff[i >> 10];
    out[i] = v;
    cur[i] = v;
  }
}

// ---------------- CSR fill ----------------
__global__ __launch_bounds__(256) void fill_kernel(const int* __restrict__ src,
                                                   const int* __restrict__ dst,
                                                   int* cur_in, int* cur_out,
                                                   int* __restrict__ csr_in_src,
                                                   int* __restrict__ csr_in_eid,
                                                   int* __restrict__ csr_out_dst, int E) {
  int i = blockIdx.x * 256 + threadIdx.x;
  if (i < E) {
    int s = src[i], d = dst[i];
    int p = atomicAdd(&cur_in[d], 1);
    csr_in_src[p] = s;
    csr_in_eid[p] = i;
    int q = atomicAdd(&cur_out[s], 1);
    csr_out_dst[q] = d;
  }
}

// ---------------- fp32 matmul: out[N,128] = A[N,128] @ W[128,128] ----------------
__global__ __launch_bounds__(256) void mm128(const float* __restrict__ A,
                                             const float* __restrict__ W,
                                             float* __restrict__ out, int nrows) {
  __shared__ float As[64][128];
  __shared__ float Ws[128][64];
  int r0 = blockIdx.x * 64;
  int cb = blockIdx.y * 64;
  int tid = threadIdx.x;

#pragma unroll
  for (int i = 0; i < 8; i++) {
    int v = tid + 256 * i;
    int k = v >> 4, c4 = (v & 15) << 2;
    *(float4*)(&Ws[k][c4]) = *(const float4*)(W + k * FDIM + cb + c4);
  }
#pragma unroll
  for (int i = 0; i < 8; i++) {
    int v = tid + 256 * i;
    int r = v >> 5, k4 = (v & 31) << 2;
    int row = r0 + r;
    float4 a;
    if (row < nrows) a = *(const float4*)(A + (size_t)row * FDIM + k4);
    else a = make_float4(0.f, 0.f, 0.f, 0.f);
    int swz = ((r >> 2) & 7) << 2;
    *(float4*)(&As[r][k4 ^ swz]) = a;
  }
  __syncthreads();

  int tx = tid & 15, ty = tid >> 4;
  int rbase = ty * 4;
  int swz = (ty & 7) << 2;
  float acc[4][4] = {};
#pragma unroll 8
  for (int k = 0; k < 128; k++) {
    int kx = k ^ swz;
    float a0 = As[rbase + 0][kx];
    float a1 = As[rbase + 1][kx];
    float a2 = As[rbase + 2][kx];
    float a3 = As[rbase + 3][kx];
    float4 w = *(float4*)(&Ws[k][tx * 4]);
    acc[0][0] += a0 * w.x; acc[0][1] += a0 * w.y; acc[0][2] += a0 * w.z; acc[0][3] += a0 * w.w;
    acc[1][0] += a1 * w.x; acc[1][1] += a1 * w.y; acc[1][2] += a1 * w.z; acc[1][3] += a1 * w.w;
    acc[2][0] += a2 * w.x; acc[2][1] += a2 * w.y; acc[2][2] += a2 * w.z; acc[2][3] += a2 * w.w;
    acc[3][0] += a3 * w.x; acc[3][1] += a3 * w.y; acc[3][2] += a3 * w.z; acc[3][3] += a3 * w.w;
  }
#pragma unroll
  for (int rr = 0; rr < 4; rr++) {
    int row = r0 + rbase + rr;
    if (row < nrows) {
      float4 o = make_float4(acc[rr][0], acc[rr][1], acc[rr][2], acc[rr][3]);
      *(float4*)(out + (size_t)row * FDIM + cb + tx * 4) = o;
    }
  }
}

// ---------------- GCN aggregation: float4 gather, 32 lanes/node, 4 nodes/block ----------------
__global__ __launch_bounds__(128) void gcn_gather4(const float4* __restrict__ tin,
                                                   const float4* __restrict__ tout,
                                                   const int* __restrict__ rp_in,
                                                   const int* __restrict__ deg_in,
                                                   const int* __restrict__ adj_in,
                                                   const int* __restrict__ rp_out,
                                                   const int* __restrict__ deg_out,
                                                   const int* __restrict__ adj_out,
                                                   const float* __restrict__ dinv_in,
                                                   const float* __restrict__ dinv_out,
                                                   const float* __restrict__ bin,
                                                   const float* __restrict__ bout,
                                                   float4* __restrict__ outp, int N) {
  int grp = threadIdx.x >> 5, lane = threadIdx.x & 31;
  int d = blockIdx.x * 4 + grp;
  if (d >= N) return;
  float wi = 0.5f * dinv_in[d], wo = 0.5f * dinv_out[d];
  float4 acc = make_float4(0.f, 0.f, 0.f, 0.f);
  int p = rp_in[d], n1 = deg_in[d];
  for (int k = 0; k < n1; k++) {
    int s = adj_in[p + k];
    float w = wi * dinv_in[s];
    float4 v = tin[(size_t)s * 32 + lane];
    acc.x += w * v.x; acc.y += w * v.y; acc.z += w * v.z; acc.w += w * v.w;
  }
  int q = rp_out[d], n2 = deg_out[d];
  for (int k = 0; k < n2; k++) {
    int s = adj_out[q + k];
    float w = wo * dinv_out[s];
    float4 v = tout[(size_t)s * 32 + lane];
    acc.x += w * v.x; acc.y += w * v.y; acc.z += w * v.z; acc.w += w * v.w;
  }
  const float4* b1 = (const float4*)bin;
  const float4* b2 = (const float4*)bout;
  float4 ba = b1[lane], bb = b2[lane];
  float4 o;
  o.x = acc.x + 0.5f * (ba.x + bb.x);
  o.y = acc.y + 0.5f * (ba.y + bb.y);
  o.z = acc.z + 0.5f * (ba.z + bb.z);
  o.w = acc.w + 0.5f * (ba.w + bb.w);
  o.x = o.x > 0.f ? o.x : 0.f;
  o.y = o.y > 0.f ? o.y : 0.f;
  o.z = o.z > 0.f ? o.z : 0.f;
  o.w = o.w > 0.f ? o.w : 0.f;
  outp[(size_t)d * 32 + lane] = o;
}

// ---------------- GATv2 logits: e-parallel, one thread per (edge, head) ----------------
__global__ __launch_bounds__(256) void gat_logits(const float* __restrict__ gl,
                                                  const float* __restrict__ gr,
                                                  const int* __restrict__ src,
                                                  const int* __restrict__ dst,
                                                  const float* __restrict__ eattr,
                                                  const float* __restrict__ we,
                                                  const float* __restrict__ att,
                                                  float* __restrict__ elog,
                                                  int E, int N) {
  __shared__ float swe[128], satt[128];
  int t = threadIdx.x;
  if (t < 128) { swe[t] = we[t]; satt[t] = att[t]; }
  __syncthreads();
  int tot = (E + N) * 4;
  int idx = blockIdx.x * 256 + t;
  if (idx >= tot) return;
  int e = idx >> 2, h = idx & 3;
  int s, d; float ea;
  if (e < E) { s = src[e]; d = dst[e]; ea = eattr[e]; }
  else { s = e - E; d = s; ea = 1.0f; }
  const float4* glp = (const float4*)(gl + (size_t)s * FDIM + h * 32);
  const float4* grp = (const float4*)(gr + (size_t)d * FDIM + h * 32);
  float acc = 0.f;
#pragma unroll
  for (int q = 0; q < 8; q++) {
    float4 a = glp[q], b = grp[q];
    const float* wp = &swe[h * 32 + q * 4];
    const float* ap = &satt[h * 32 + q * 4];
    float v;
    v = a.x + b.x + ea * wp[0]; v = v > 0.f ? v : 0.2f * v; acc += v * ap[0];
    v = a.y + b.y + ea * wp[1]; v = v > 0.f ? v : 0.2f * v; acc += v * ap[1];
    v = a.z + b.z + ea * wp[2]; v = v > 0.f ? v : 0.2f * v; acc += v * ap[2];
    v = a.w + b.w + ea * wp[3]; v = v > 0.f ? v : 0.2f * v; acc += v * ap[3];
  }
  elog[idx] = acc;
}

// ---------------- GATv2 aggregation: 32 lanes/node (float4), two-pass softmax ----------------
__global__ __launch_bounds__(128) void gat_aggr(const float4* __restrict__ gl,
                                                const float* __restrict__ elog,
                                                const int* __restrict__ rp,
                                                const int* __restrict__ deg,
                                                const int* __restrict__ adj_src,
                                                const int* __restrict__ adj_eid,
                                                const float* __restrict__ gatb,
                                                float4* __restrict__ outp, int E, int N) {
  int grp = threadIdx.x >> 5, lane = threadIdx.x & 31;
  int d = blockIdx.x * 4 + grp;
  if (d >= N) return;
  int h = lane >> 3;  // head of this feature quad
  int p = rp[d], n1 = deg[d];
  // pass 1: max logit for this head over incoming edges + self loop
  float m = elog[(size_t)(E + d) * 4 + h];
  for (int k = 0; k < n1; k++) {
    int e = adj_eid[p + k];
    m = fmaxf(m, elog[(size_t)e * 4 + h]);
  }
  // pass 2: exp-weighted gather
  float denom = 0.f;
  float4 o = make_float4(0.f, 0.f, 0.f, 0.f);
  for (int k = 0; k <= n1; k++) {
    int s, e;
    if (k < n1) { s = adj_src[p + k]; e = adj_eid[p + k]; }
    else { s = d; e = E + d; }
    float w = expf(elog[(size_t)e * 4 + h] - m);
    float4 g = gl[(size_t)s * 32 + lane];
    denom += w;
    o.x += w * g.x; o.y += w * g.y; o.z += w * g.z; o.w += w * g.w;
  }
  const float4* b4 = (const float4*)gatb;
  float4 bb = b4[lane];
  float4 r;
  r.x = o.x / denom + bb.x;
  r.y = o.y / denom + bb.y;
  r.z = o.z / denom + bb.z;
  r.w = o.w / denom + bb.w;
  outp[(size_t)d * 32 + lane] = r;
}

// ---------------- mean pool (batch sorted: running-sum per contiguous chunk) ----------------
__global__ __launch_bounds__(128) void pool_kernel(const float* __restrict__ srcf,
                                                   const int* __restrict__ batch,
                                                   float* __restrict__ zb,
                                                   int colOff, int N) {
  __shared__ int sb[PCH];
  int c0 = blockIdx.x * PCH;
  int t = threadIdx.x;
  int nmax = N - c0; if (nmax > PCH) nmax = PCH;
  if (t < nmax) sb[t] = batch[c0 + t];
  __syncthreads();
  float run = 0.f;
  int gp = sb[0];
  for (int i = 0; i < nmax; i++) {
    int g = sb[i];
    if (g != gp) {
      atomicAdd(&zb[(size_t)gp * 256 + colOff + t], run);
      run = 0.f; gp = g;
    }
    run += srcf[(size_t)(c0 + i) * FDIM + t];
  }
  atomicAdd(&zb[(size_t)gp * 256 + colOff + t], run);
}

// ---------------- head ----------------
__global__ __launch_bounds__(128) void head_kernel(const float* __restrict__ zb,
                                                   const float* __restrict__ cnt,
                                                   const float* __restrict__ w1,
                                                   const float* __restrict__ b1,
                                                   const float* __restrict__ w2,
                                                   const float* __restrict__ b2,
                                                   float* __restrict__ out, int G) {
  __shared__ float z[256];
  __shared__ float y[128];
  int g = blockIdx.x, t = threadIdx.x;
  float c = cnt[g];
  float cm = c > 1.f ? c : 1.f;
  z[t]       = zb[(size_t)g * 256 + t] / cm;
  z[t + 128] = zb[(size_t)g * 256 + 128 + t] / cm;
  __syncthreads();
  float acc = b1[t];
  for (int k = 0; k < 256; k++) acc += z[k] * w1[k * 128 + t];
  y[t] = acc > 0.f ? acc : 0.f;
  __syncthreads();
  if (t < 2) {
    float o = b2[t];
    for (int j = 0; j < 128; j++) o += y[j] * w2[j * 2 + t];
    out[(size_t)g * 2 + t] = o;
  }
}

extern "C" void kernel_launch(void* const* d_in, const int* in_sizes, int n_in,
                              void* d_out, int out_size, void* d_ws, size_t ws_size,
                              hipStream_t stream) {
  const float* x     = (const float*)d_in[0];
  const int*   ei    = (const int*)d_in[1];
  const float* eattr = (const float*)d_in[2];
  const int*   batch = (const int*)d_in[3];
  const float* dwi   = (const float*)d_in[4];
  const float* dbi   = (const float*)d_in[5];
  const float* dwo   = (const float*)d_in[6];
  const float* dbo   = (const float*)d_in[7];
  const float* wl    = (const float*)d_in[8];
  const float* wr    = (const float*)d_in[9];
  const float* we    = (const float*)d_in[10];
  const float* att   = (const float*)d_in[11];
  const float* gatb  = (const float*)d_in[12];
  const float* w1    = (const float*)d_in[13];
  const float* b1    = (const float*)d_in[14];
  const float* w2    = (const float*)d_in[15];
  const float* b2    = (const float*)d_in[16];

  int N = in_sizes[0] / FDIM;
  int E = in_sizes[1] / 2;
  int G = out_size / 2;
  const int* src = ei;
  const int* dst = ei + E;

  // ---- workspace layout (4-byte elements) ----
  float* ws = (float*)d_ws;
  size_t off = 0;
  float* A        = ws + off; off += (size_t)N * FDIM;
  float* B        = ws + off; off += (size_t)N * FDIM;
  float* C        = ws + off; off += (size_t)N * FDIM;
  float* dinv2    = ws + off; off += 2 * (size_t)N;          // [dinv_in | dinv_out]
  int* deg2       = (int*)(ws + off); off += 2 * (size_t)N;  // [deg_in | deg_out]
  int* rp_in      = (int*)(ws + off); off += (size_t)N;
  int* rp_out     = (int*)(ws + off); off += (size_t)N;
  int* cur_in     = (int*)(ws + off); off += (size_t)N;
  int* cur_out    = (int*)(ws + off); off += (size_t)N;
  int* csr_in_src = (int*)(ws + off); off += (size_t)E;
  int* csr_in_eid = (int*)(ws + off); off += (size_t)E;
  int* csr_out_dst= (int*)(ws + off); off += (size_t)E;
  int* bsums      = (int*)(ws + off); off += 256;
  int* boff       = (int*)(ws + off); off += 256;
  float* elog     = ws + off; off += (size_t)(E + N) * 4;
  float* zb       = ws + off; off += (size_t)G * 256;
  float* cnt      = ws + off; off += (size_t)G;

  int* deg_in = deg2, *deg_out = deg2 + N;
  float* dinv_in = dinv2, *dinv_out = dinv2 + N;

  dim3 mmg(cdiv(N, 64), 2);
  int nb1 = cdiv(N, 1024);

  // ---- CSR build ----
  hipMemsetAsync(deg2, 0, 2 * (size_t)N * sizeof(int), stream);
  degi_kernel<<<cdiv(E, 256), 256, 0, stream>>>(src, dst, deg_in, deg_out, E);
  dinv2_kernel<<<cdiv(2LL * N, 256), 256, 0, stream>>>(deg2, dinv2, 2 * N);
  scan1<<<nb1, 256, 0, stream>>>(deg_in, rp_in, bsums, N);
  scan2<<<1, 256, 0, stream>>>(bsums, boff, nb1);
  scan3<<<cdiv(N, 256), 256, 0, stream>>>(rp_in, boff, cur_in, N);
  scan1<<<nb1, 256, 0, stream>>>(deg_out, rp_out, bsums, N);
  scan2<<<1, 256, 0, stream>>>(bsums, boff, nb1);
  scan3<<<cdiv(N, 256), 256, 0, stream>>>(rp_out, boff, cur_out, N);
  fill_kernel<<<cdiv(E, 256), 256, 0, stream>>>(src, dst, cur_in, cur_out,
                                                csr_in_src, csr_in_eid, csr_out_dst, E);

  // ---- pool counts ----
  hipMemsetAsync(zb, 0, ((size_t)G * 256 + G) * sizeof(float), stream);
  cnt_kernel<<<cdiv(N, 256), 256, 0, stream>>>(batch, cnt, N);

  // ---- DirGNN layer 0 (h = x) ----
  mm128<<<mmg, 256, 0, stream>>>(x, dwi, B, N);
  mm128<<<mmg, 256, 0, stream>>>(x, dwo, C, N);
  gcn_gather4<<<cdiv(N, 4), 128, 0, stream>>>((const float4*)B, (const float4*)C,
                                              rp_in, deg_in, csr_in_src,
                                              rp_out, deg_out, csr_out_dst,
                                              dinv_in, dinv_out, dbi, dbo, (float4*)A, N);
  // ---- DirGNN layer 1 (h = A) ----
  mm128<<<mmg, 256, 0, stream>>>(A, dwi + 16384, B, N);
  mm128<<<mmg, 256, 0, stream>>>(A, dwo + 16384, C, N);
  gcn_gather4<<<cdiv(N, 4), 128, 0, stream>>>((const float4*)B, (const float4*)C,
                                              rp_in, deg_in, csr_in_src,
                                              rp_out, deg_out, csr_out_dst,
                                              dinv_in, dinv_out, dbi + 128, dbo + 128, (float4*)A, N);
  // pool x1 -> zb[:, 0:128]
  pool_kernel<<<cdiv(N, PCH), 128, 0, stream>>>(A, batch, zb, 0, N);

  // ---- GATv2 branch (on original x) ----
  mm128<<<mmg, 256, 0, stream>>>(x, wl, B, N);   // gl (source transform)
  mm128<<<mmg, 256, 0, stream>>>(x, wr, C, N);   // gr (target transform)
  int tot4 = (E + N) * 4;
  gat_logits<<<cdiv(tot4, 256), 256, 0, stream>>>(B, C, src, dst, eattr, we, att, elog, E, N);
  gat_aggr<<<cdiv(N, 4), 128, 0, stream>>>((const float4*)B, elog, rp_in, deg_in,
                                           csr_in_src, csr_in_eid, gatb, (float4*)A, E, N);
  // pool x2 -> zb[:, 128:256]
  pool_kernel<<<cdiv(N, PCH), 128, 0, stream>>>(A, batch, zb, 128, N);

  // head
  head_kernel<<<G, 128, 0, stream>>>(zb, cnt, w1, b1, w2, b2, (float*)d_out, G);
}

// Round 4
// 1418.301 us; speedup vs baseline: 2.3461x; 1.1818x over previous
//
#include <hip/hip_runtime.h>
#include <cstdint>

#define FDIM 128
#define PCH 64

static inline int cdiv(long long a, long long b) { return (int)((a + b - 1) / b); }

// ---------------- degree histograms (int) ----------------
__global__ __launch_bounds__(256) void degi_kernel(const int* __restrict__ src,
                                                   const int* __restrict__ dst,
                                                   int* deg_in, int* deg_out, int E) {
  int i = blockIdx.x * 256 + threadIdx.x;
  if (i < E) {
    atomicAdd(&deg_in[dst[i]], 1);
    atomicAdd(&deg_out[src[i]], 1);
  }
}

// dinv[i] = deg>0 ? 1/sqrt(deg) : 0
__global__ __launch_bounds__(256) void dinv2_kernel(const int* __restrict__ degs,
                                                    float* __restrict__ dinv, int n2) {
  int i = blockIdx.x * 256 + threadIdx.x;
  if (i < n2) {
    int v = degs[i];
    dinv[i] = v > 0 ? 1.0f / sqrtf((float)v) : 0.f;
  }
}

__global__ __launch_bounds__(256) void cnt_kernel(const int* __restrict__ batch, float* cnt, int N) {
  int i = blockIdx.x * 256 + threadIdx.x;
  if (i < N) atomicAdd(&cnt[batch[i]], 1.0f);
}

// ---------------- hierarchical exclusive scan (n <= 256*1024) ----------------
__global__ __launch_bounds__(256) void scan1(const int* __restrict__ in, int* __restrict__ out,
                                             int* __restrict__ bsums, int n) {
  __shared__ int tmp[256];
  int t = threadIdx.x;
  int base = blockIdx.x * 1024 + t * 4;
  int a[4];
#pragma unroll
  for (int j = 0; j < 4; j++) a[j] = (base + j < n) ? in[base + j] : 0;
  int s = a[0] + a[1] + a[2] + a[3];
  tmp[t] = s;
  __syncthreads();
  for (int off = 1; off < 256; off <<= 1) {
    int v = (t >= off) ? tmp[t - off] : 0;
    __syncthreads();
    tmp[t] += v;
    __syncthreads();
  }
  int excl = tmp[t] - s;
  int run = excl;
#pragma unroll
  for (int j = 0; j < 4; j++) {
    if (base + j < n) out[base + j] = run;
    run += a[j];
  }
  if (t == 255) bsums[blockIdx.x] = tmp[255];
}

__global__ __launch_bounds__(256) void scan2(const int* __restrict__ bsums,
                                             int* __restrict__ boff, int nb) {
  __shared__ int tmp[256];
  int t = threadIdx.x;
  int s = (t < nb) ? bsums[t] : 0;
  tmp[t] = s;
  __syncthreads();
  for (int off = 1; off < 256; off <<= 1) {
    int v = (t >= off) ? tmp[t - off] : 0;
    __syncthreads();
    tmp[t] += v;
    __syncthreads();
  }
  if (t < nb) boff[t] = tmp[t] - s;
}

__global__ __launch_bounds__(256) void scan3(int* __restrict__ out, const int* __restrict__ boff,
                                             int* __restrict__ cur, int n) {
  int i = blockIdx.x * 256 + threadIdx.x;
  if (i < n) {
    int v = out[i] + boff[i >> 10];
    out[i] = v;
    cur[i] = v;
  }
}

// ---------------- CSR fill ----------------
__global__ __launch_bounds__(256) void fill_kernel(const int* __restrict__ src,
                                                   const int* __restrict__ dst,
                                                   int* cur_in, int* cur_out,
                                                   int* __restrict__ csr_in_src,
                                                   int* __restrict__ csr_in_eid,
                                                   int* __restrict__ csr_out_dst, int E) {
  int i = blockIdx.x * 256 + threadIdx.x;
  if (i < E) {
    int s = src[i], d = dst[i];
    int p = atomicAdd(&cur_in[d], 1);
    csr_in_src[p] = s;
    csr_in_eid[p] = i;
    int q = atomicAdd(&cur_out[s], 1);
    csr_out_dst[q] = d;
  }
}

// ---------------- fp32 matmul: out[N,128] = A[N,128] @ W[128,128] ----------------
__global__ __launch_bounds__(256) void mm128(const float* __restrict__ A,
                                             const float* __restrict__ W,
                                             float* __restrict__ out, int nrows) {
  __shared__ float As[64][128];
  __shared__ float Ws[128][64];
  int r0 = blockIdx.x * 64;
  int cb = blockIdx.y * 64;
  int tid = threadIdx.x;

#pragma unroll
  for (int i = 0; i < 8; i++) {
    int v = tid + 256 * i;
    int k = v >> 4, c4 = (v & 15) << 2;
    *(float4*)(&Ws[k][c4]) = *(const float4*)(W + k * FDIM + cb + c4);
  }
#pragma unroll
  for (int i = 0; i < 8; i++) {
    int v = tid + 256 * i;
    int r = v >> 5, k4 = (v & 31) << 2;
    int row = r0 + r;
    float4 a;
    if (row < nrows) a = *(const float4*)(A + (size_t)row * FDIM + k4);
    else a = make_float4(0.f, 0.f, 0.f, 0.f);
    int swz = ((r >> 2) & 7) << 2;
    *(float4*)(&As[r][k4 ^ swz]) = a;
  }
  __syncthreads();

  int tx = tid & 15, ty = tid >> 4;
  int rbase = ty * 4;
  int swz = (ty & 7) << 2;
  float acc[4][4] = {};
#pragma unroll 8
  for (int k = 0; k < 128; k++) {
    int kx = k ^ swz;
    float a0 = As[rbase + 0][kx];
    float a1 = As[rbase + 1][kx];
    float a2 = As[rbase + 2][kx];
    float a3 = As[rbase + 3][kx];
    float4 w = *(float4*)(&Ws[k][tx * 4]);
    acc[0][0] += a0 * w.x; acc[0][1] += a0 * w.y; acc[0][2] += a0 * w.z; acc[0][3] += a0 * w.w;
    acc[1][0] += a1 * w.x; acc[1][1] += a1 * w.y; acc[1][2] += a1 * w.z; acc[1][3] += a1 * w.w;
    acc[2][0] += a2 * w.x; acc[2][1] += a2 * w.y; acc[2][2] += a2 * w.z; acc[2][3] += a2 * w.w;
    acc[3][0] += a3 * w.x; acc[3][1] += a3 * w.y; acc[3][2] += a3 * w.z; acc[3][3] += a3 * w.w;
  }
#pragma unroll
  for (int rr = 0; rr < 4; rr++) {
    int row = r0 + rbase + rr;
    if (row < nrows) {
      float4 o = make_float4(acc[rr][0], acc[rr][1], acc[rr][2], acc[rr][3]);
      *(float4*)(out + (size_t)row * FDIM + cb + tx * 4) = o;
    }
  }
}

// ---------------- GCN aggregation: float4 gather, 32 lanes/node, unroll-4 MLP ----------------
__global__ __launch_bounds__(128) void gcn_gather4(const float4* __restrict__ tin,
                                                   const float4* __restrict__ tout,
                                                   const int* __restrict__ rp_in,
                                                   const int* __restrict__ deg_in,
                                                   const int* __restrict__ adj_in,
                                                   const int* __restrict__ rp_out,
                                                   const int* __restrict__ deg_out,
                                                   const int* __restrict__ adj_out,
                                                   const float* __restrict__ dinv_in,
                                                   const float* __restrict__ dinv_out,
                                                   const float* __restrict__ bin,
                                                   const float* __restrict__ bout,
                                                   float4* __restrict__ outp, int N) {
  int grp = threadIdx.x >> 5, lane = threadIdx.x & 31;
  int d = blockIdx.x * 4 + grp;
  if (d >= N) return;
  float wi = 0.5f * dinv_in[d], wo = 0.5f * dinv_out[d];
  float4 a0 = make_float4(0.f, 0.f, 0.f, 0.f);
  float4 a1 = a0, a2 = a0, a3 = a0;

  int p = rp_in[d], n1 = deg_in[d];
  int k = 0;
  for (; k + 4 <= n1; k += 4) {
    int s0 = adj_in[p + k], s1 = adj_in[p + k + 1], s2 = adj_in[p + k + 2], s3 = adj_in[p + k + 3];
    float w0 = wi * dinv_in[s0], w1 = wi * dinv_in[s1], w2 = wi * dinv_in[s2], w3 = wi * dinv_in[s3];
    float4 v0 = tin[(size_t)s0 * 32 + lane];
    float4 v1 = tin[(size_t)s1 * 32 + lane];
    float4 v2 = tin[(size_t)s2 * 32 + lane];
    float4 v3 = tin[(size_t)s3 * 32 + lane];
    a0.x += w0 * v0.x; a0.y += w0 * v0.y; a0.z += w0 * v0.z; a0.w += w0 * v0.w;
    a1.x += w1 * v1.x; a1.y += w1 * v1.y; a1.z += w1 * v1.z; a1.w += w1 * v1.w;
    a2.x += w2 * v2.x; a2.y += w2 * v2.y; a2.z += w2 * v2.z; a2.w += w2 * v2.w;
    a3.x += w3 * v3.x; a3.y += w3 * v3.y; a3.z += w3 * v3.z; a3.w += w3 * v3.w;
  }
  for (; k < n1; k++) {
    int s = adj_in[p + k];
    float w = wi * dinv_in[s];
    float4 v = tin[(size_t)s * 32 + lane];
    a0.x += w * v.x; a0.y += w * v.y; a0.z += w * v.z; a0.w += w * v.w;
  }

  int q = rp_out[d], n2 = deg_out[d];
  k = 0;
  for (; k + 4 <= n2; k += 4) {
    int s0 = adj_out[q + k], s1 = adj_out[q + k + 1], s2 = adj_out[q + k + 2], s3 = adj_out[q + k + 3];
    float w0 = wo * dinv_out[s0], w1 = wo * dinv_out[s1], w2 = wo * dinv_out[s2], w3 = wo * dinv_out[s3];
    float4 v0 = tout[(size_t)s0 * 32 + lane];
    float4 v1 = tout[(size_t)s1 * 32 + lane];
    float4 v2 = tout[(size_t)s2 * 32 + lane];
    float4 v3 = tout[(size_t)s3 * 32 + lane];
    a0.x += w0 * v0.x; a0.y += w0 * v0.y; a0.z += w0 * v0.z; a0.w += w0 * v0.w;
    a1.x += w1 * v1.x; a1.y += w1 * v1.y; a1.z += w1 * v1.z; a1.w += w1 * v1.w;
    a2.x += w2 * v2.x; a2.y += w2 * v2.y; a2.z += w2 * v2.z; a2.w += w2 * v2.w;
    a3.x += w3 * v3.x; a3.y += w3 * v3.y; a3.z += w3 * v3.z; a3.w += w3 * v3.w;
  }
  for (; k < n2; k++) {
    int s = adj_out[q + k];
    float w = wo * dinv_out[s];
    float4 v = tout[(size_t)s * 32 + lane];
    a0.x += w * v.x; a0.y += w * v.y; a0.z += w * v.z; a0.w += w * v.w;
  }

  float4 acc;
  acc.x = (a0.x + a1.x) + (a2.x + a3.x);
  acc.y = (a0.y + a1.y) + (a2.y + a3.y);
  acc.z = (a0.z + a1.z) + (a2.z + a3.z);
  acc.w = (a0.w + a1.w) + (a2.w + a3.w);

  const float4* b1 = (const float4*)bin;
  const float4* b2 = (const float4*)bout;
  float4 ba = b1[lane], bb = b2[lane];
  float4 o;
  o.x = acc.x + 0.5f * (ba.x + bb.x);
  o.y = acc.y + 0.5f * (ba.y + bb.y);
  o.z = acc.z + 0.5f * (ba.z + bb.z);
  o.w = acc.w + 0.5f * (ba.w + bb.w);
  o.x = o.x > 0.f ? o.x : 0.f;
  o.y = o.y > 0.f ? o.y : 0.f;
  o.z = o.z > 0.f ? o.z : 0.f;
  o.w = o.w > 0.f ? o.w : 0.f;
  outp[(size_t)d * 32 + lane] = o;
}

// ---------------- GATv2: fused online-softmax, 32 lanes/node, float4, unroll-2 ----------------
// lane layout: head h = lane>>3; channels c = (lane&7)*4 .. +3.
// logit reduce = 3 shfl_xor within the 8-lane head group.
__global__ __launch_bounds__(128) void gat_fused2(const float4* __restrict__ gl,
                                                  const float4* __restrict__ gr,
                                                  const int* __restrict__ rp,
                                                  const int* __restrict__ deg,
                                                  const int* __restrict__ adj_src,
                                                  const int* __restrict__ adj_eid,
                                                  const float* __restrict__ eattr,
                                                  const float* __restrict__ we,
                                                  const float* __restrict__ att,
                                                  const float* __restrict__ gatb,
                                                  float4* __restrict__ outp, int N) {
  int grp = threadIdx.x >> 5, lane = threadIdx.x & 31;
  int d = blockIdx.x * 4 + grp;
  if (d >= N) return;

  float4 grv = gr[(size_t)d * 32 + lane];
  float4 wev = ((const float4*)we)[lane];
  float4 atv = ((const float4*)att)[lane];

  int p = rp[d], n1 = deg[d];
  float m = -1e30f, den = 0.f;
  float4 o = make_float4(0.f, 0.f, 0.f, 0.f);

#define GAT_LOGIT(g4, ea, pv)                                                     \
  {                                                                               \
    float vx = g4.x + grv.x + (ea) * wev.x; vx = vx > 0.f ? vx : 0.2f * vx;       \
    float vy = g4.y + grv.y + (ea) * wev.y; vy = vy > 0.f ? vy : 0.2f * vy;       \
    float vz = g4.z + grv.z + (ea) * wev.z; vz = vz > 0.f ? vz : 0.2f * vz;       \
    float vw = g4.w + grv.w + (ea) * wev.w; vw = vw > 0.f ? vw : 0.2f * vw;       \
    pv = vx * atv.x + vy * atv.y + vz * atv.z + vw * atv.w;                       \
    pv += __shfl_xor(pv, 1);                                                      \
    pv += __shfl_xor(pv, 2);                                                      \
    pv += __shfl_xor(pv, 4);                                                      \
  }

#define GAT_UPDATE(g4, pv)                                                        \
  {                                                                               \
    float mn = fmaxf(m, pv);                                                      \
    float sc = expf(m - mn);                                                      \
    float w = expf(pv - mn);                                                      \
    den = den * sc + w;                                                           \
    o.x = o.x * sc + w * g4.x;                                                    \
    o.y = o.y * sc + w * g4.y;                                                    \
    o.z = o.z * sc + w * g4.z;                                                    \
    o.w = o.w * sc + w * g4.w;                                                    \
    m = mn;                                                                       \
  }

  int k = 0;
  for (; k + 2 <= n1; k += 2) {
    int s0 = adj_src[p + k], s1 = adj_src[p + k + 1];
    int e0 = adj_eid[p + k], e1 = adj_eid[p + k + 1];
    float ea0 = eattr[e0], ea1 = eattr[e1];
    float4 g0 = gl[(size_t)s0 * 32 + lane];
    float4 g1 = gl[(size_t)s1 * 32 + lane];
    float pv0, pv1;
    GAT_LOGIT(g0, ea0, pv0);
    GAT_LOGIT(g1, ea1, pv1);
    GAT_UPDATE(g0, pv0);
    GAT_UPDATE(g1, pv1);
  }
  if (k < n1) {
    int s = adj_src[p + k], e = adj_eid[p + k];
    float ea = eattr[e];
    float4 g = gl[(size_t)s * 32 + lane];
    float pv;
    GAT_LOGIT(g, ea, pv);
    GAT_UPDATE(g, pv);
  }
  {  // self loop: s = d, ea = 1.0
    float4 g = gl[(size_t)d * 32 + lane];
    float pv;
    GAT_LOGIT(g, 1.0f, pv);
    GAT_UPDATE(g, pv);
  }
#undef GAT_LOGIT
#undef GAT_UPDATE

  float4 bb = ((const float4*)gatb)[lane];
  float4 r;
  r.x = o.x / den + bb.x;
  r.y = o.y / den + bb.y;
  r.z = o.z / den + bb.z;
  r.w = o.w / den + bb.w;
  outp[(size_t)d * 32 + lane] = r;
}

// ---------------- mean pool (batch sorted: running-sum per contiguous chunk) ----------------
__global__ __launch_bounds__(128) void pool_kernel(const float* __restrict__ srcf,
                                                   const int* __restrict__ batch,
                                                   float* __restrict__ zb,
                                                   int colOff, int N) {
  __shared__ int sb[PCH];
  int c0 = blockIdx.x * PCH;
  int t = threadIdx.x;
  int nmax = N - c0; if (nmax > PCH) nmax = PCH;
  if (t < nmax) sb[t] = batch[c0 + t];
  __syncthreads();
  float run = 0.f;
  int gp = sb[0];
  for (int i = 0; i < nmax; i++) {
    int g = sb[i];
    if (g != gp) {
      atomicAdd(&zb[(size_t)gp * 256 + colOff + t], run);
      run = 0.f; gp = g;
    }
    run += srcf[(size_t)(c0 + i) * FDIM + t];
  }
  atomicAdd(&zb[(size_t)gp * 256 + colOff + t], run);
}

// ---------------- head ----------------
__global__ __launch_bounds__(128) void head_kernel(const float* __restrict__ zb,
                                                   const float* __restrict__ cnt,
                                                   const float* __restrict__ w1,
                                                   const float* __restrict__ b1,
                                                   const float* __restrict__ w2,
                                                   const float* __restrict__ b2,
                                                   float* __restrict__ out, int G) {
  __shared__ float z[256];
  __shared__ float y[128];
  int g = blockIdx.x, t = threadIdx.x;
  float c = cnt[g];
  float cm = c > 1.f ? c : 1.f;
  z[t]       = zb[(size_t)g * 256 + t] / cm;
  z[t + 128] = zb[(size_t)g * 256 + 128 + t] / cm;
  __syncthreads();
  float acc = b1[t];
  for (int k = 0; k < 256; k++) acc += z[k] * w1[k * 128 + t];
  y[t] = acc > 0.f ? acc : 0.f;
  __syncthreads();
  if (t < 2) {
    float o = b2[t];
    for (int j = 0; j < 128; j++) o += y[j] * w2[j * 2 + t];
    out[(size_t)g * 2 + t] = o;
  }
}

extern "C" void kernel_launch(void* const* d_in, const int* in_sizes, int n_in,
                              void* d_out, int out_size, void* d_ws, size_t ws_size,
                              hipStream_t stream) {
  const float* x     = (const float*)d_in[0];
  const int*   ei    = (const int*)d_in[1];
  const float* eattr = (const float*)d_in[2];
  const int*   batch = (const int*)d_in[3];
  const float* dwi   = (const float*)d_in[4];
  const float* dbi   = (const float*)d_in[5];
  const float* dwo   = (const float*)d_in[6];
  const float* dbo   = (const float*)d_in[7];
  const float* wl    = (const float*)d_in[8];
  const float* wr    = (const float*)d_in[9];
  const float* we    = (const float*)d_in[10];
  const float* att   = (const float*)d_in[11];
  const float* gatb  = (const float*)d_in[12];
  const float* w1    = (const float*)d_in[13];
  const float* b1    = (const float*)d_in[14];
  const float* w2    = (const float*)d_in[15];
  const float* b2    = (const float*)d_in[16];

  int N = in_sizes[0] / FDIM;
  int E = in_sizes[1] / 2;
  int G = out_size / 2;
  const int* src = ei;
  const int* dst = ei + E;

  // ---- workspace layout (4-byte elements) ----
  float* ws = (float*)d_ws;
  size_t off = 0;
  float* A        = ws + off; off += (size_t)N * FDIM;
  float* B        = ws + off; off += (size_t)N * FDIM;
  float* C        = ws + off; off += (size_t)N * FDIM;
  float* dinv2    = ws + off; off += 2 * (size_t)N;          // [dinv_in | dinv_out]
  int* deg2       = (int*)(ws + off); off += 2 * (size_t)N;  // [deg_in | deg_out]
  int* rp_in      = (int*)(ws + off); off += (size_t)N;
  int* rp_out     = (int*)(ws + off); off += (size_t)N;
  int* cur_in     = (int*)(ws + off); off += (size_t)N;
  int* cur_out    = (int*)(ws + off); off += (size_t)N;
  int* csr_in_src = (int*)(ws + off); off += (size_t)E;
  int* csr_in_eid = (int*)(ws + off); off += (size_t)E;
  int* csr_out_dst= (int*)(ws + off); off += (size_t)E;
  int* bsums      = (int*)(ws + off); off += 256;
  int* boff       = (int*)(ws + off); off += 256;
  float* zb       = ws + off; off += (size_t)G * 256;
  float* cnt      = ws + off; off += (size_t)G;

  int* deg_in = deg2, *deg_out = deg2 + N;
  float* dinv_in = dinv2, *dinv_out = dinv2 + N;

  dim3 mmg(cdiv(N, 64), 2);
  int nb1 = cdiv(N, 1024);

  // ---- CSR build ----
  hipMemsetAsync(deg2, 0, 2 * (size_t)N * sizeof(int), stream);
  degi_kernel<<<cdiv(E, 256), 256, 0, stream>>>(src, dst, deg_in, deg_out, E);
  dinv2_kernel<<<cdiv(2LL * N, 256), 256, 0, stream>>>(deg2, dinv2, 2 * N);
  scan1<<<nb1, 256, 0, stream>>>(deg_in, rp_in, bsums, N);
  scan2<<<1, 256, 0, stream>>>(bsums, boff, nb1);
  scan3<<<cdiv(N, 256), 256, 0, stream>>>(rp_in, boff, cur_in, N);
  scan1<<<nb1, 256, 0, stream>>>(deg_out, rp_out, bsums, N);
  scan2<<<1, 256, 0, stream>>>(bsums, boff, nb1);
  scan3<<<cdiv(N, 256), 256, 0, stream>>>(rp_out, boff, cur_out, N);
  fill_kernel<<<cdiv(E, 256), 256, 0, stream>>>(src, dst, cur_in, cur_out,
                                                csr_in_src, csr_in_eid, csr_out_dst, E);

  // ---- pool counts ----
  hipMemsetAsync(zb, 0, ((size_t)G * 256 + G) * sizeof(float), stream);
  cnt_kernel<<<cdiv(N, 256), 256, 0, stream>>>(batch, cnt, N);

  // ---- DirGNN layer 0 (h = x) ----
  mm128<<<mmg, 256, 0, stream>>>(x, dwi, B, N);
  mm128<<<mmg, 256, 0, stream>>>(x, dwo, C, N);
  gcn_gather4<<<cdiv(N, 4), 128, 0, stream>>>((const float4*)B, (const float4*)C,
                                              rp_in, deg_in, csr_in_src,
                                              rp_out, deg_out, csr_out_dst,
                                              dinv_in, dinv_out, dbi, dbo, (float4*)A, N);
  // ---- DirGNN layer 1 (h = A) ----
  mm128<<<mmg, 256, 0, stream>>>(A, dwi + 16384, B, N);
  mm128<<<mmg, 256, 0, stream>>>(A, dwo + 16384, C, N);
  gcn_gather4<<<cdiv(N, 4), 128, 0, stream>>>((const float4*)B, (const float4*)C,
                                              rp_in, deg_in, csr_in_src,
                                              rp_out, deg_out, csr_out_dst,
                                              dinv_in, dinv_out, dbi + 128, dbo + 128, (float4*)A, N);
  // pool x1 -> zb[:, 0:128]
  pool_kernel<<<cdiv(N, PCH), 128, 0, stream>>>(A, batch, zb, 0, N);

  // ---- GATv2 branch (on original x) ----
  mm128<<<mmg, 256, 0, stream>>>(x, wl, B, N);   // gl (source transform)
  mm128<<<mmg, 256, 0, stream>>>(x, wr, C, N);   // gr (target transform)
  gat_fused2<<<cdiv(N, 4), 128, 0, stream>>>((const float4*)B, (const float4*)C,
                                             rp_in, deg_in, csr_in_src, csr_in_eid,
                                             eattr, we, att, gatb, (float4*)A, N);
  // pool x2 -> zb[:, 128:256]
  pool_kernel<<<cdiv(N, PCH), 128, 0, stream>>>(A, batch, zb, 128, N);

  // head
  head_kernel<<<G, 128, 0, stream>>>(zb, cnt, w1, b1, w2, b2, (float*)d_out, G);
}

// Round 5
// 1332.900 us; speedup vs baseline: 2.4964x; 1.0641x over previous
//
#include <hip/hip_runtime.h>
#include <cstdint>

#define FDIM 128
#define PCH 256

static inline int cdiv(long long a, long long b) { return (int)((a + b - 1) / b); }

// ---------------- degree histograms (int) ----------------
__global__ __launch_bounds__(256) void degi_kernel(const int* __restrict__ src,
                                                   const int* __restrict__ dst,
                                                   int* deg_in, int* deg_out, int E) {
  int i = blockIdx.x * 256 + threadIdx.x;
  if (i < E) {
    atomicAdd(&deg_in[dst[i]], 1);
    atomicAdd(&deg_out[src[i]], 1);
  }
}

// dinv[i] = deg>0 ? 1/sqrt(deg) : 0
__global__ __launch_bounds__(256) void dinv2_kernel(const int* __restrict__ degs,
                                                    float* __restrict__ dinv, int n2) {
  int i = blockIdx.x * 256 + threadIdx.x;
  if (i < n2) {
    int v = degs[i];
    dinv[i] = v > 0 ? 1.0f / sqrtf((float)v) : 0.f;
  }
}

// batch is sorted: cnt[g] = upper_bound(g) - lower_bound(g). No atomics.
__global__ __launch_bounds__(256) void cnt_sorted(const int* __restrict__ batch,
                                                  float* __restrict__ cnt, int N, int G) {
  int g = blockIdx.x * 256 + threadIdx.x;
  if (g >= G) return;
  int lo = 0, hi = N;
  while (lo < hi) { int mid = (lo + hi) >> 1; if (batch[mid] < g) lo = mid + 1; else hi = mid; }
  int lo2 = lo, hi2 = N;
  while (lo2 < hi2) { int mid = (lo2 + hi2) >> 1; if (batch[mid] <= g) lo2 = mid + 1; else hi2 = mid; }
  cnt[g] = (float)(lo2 - lo);
}

// ---------------- hierarchical exclusive scan (n <= 256*1024) ----------------
__global__ __launch_bounds__(256) void scan1(const int* __restrict__ in, int* __restrict__ out,
                                             int* __restrict__ bsums, int n) {
  __shared__ int tmp[256];
  int t = threadIdx.x;
  int base = blockIdx.x * 1024 + t * 4;
  int a[4];
#pragma unroll
  for (int j = 0; j < 4; j++) a[j] = (base + j < n) ? in[base + j] : 0;
  int s = a[0] + a[1] + a[2] + a[3];
  tmp[t] = s;
  __syncthreads();
  for (int off = 1; off < 256; off <<= 1) {
    int v = (t >= off) ? tmp[t - off] : 0;
    __syncthreads();
    tmp[t] += v;
    __syncthreads();
  }
  int excl = tmp[t] - s;
  int run = excl;
#pragma unroll
  for (int j = 0; j < 4; j++) {
    if (base + j < n) out[base + j] = run;
    run += a[j];
  }
  if (t == 255) bsums[blockIdx.x] = tmp[255];
}

__global__ __launch_bounds__(256) void scan2(const int* __restrict__ bsums,
                                             int* __restrict__ boff, int nb) {
  __shared__ int tmp[256];
  int t = threadIdx.x;
  int s = (t < nb) ? bsums[t] : 0;
  tmp[t] = s;
  __syncthreads();
  for (int off = 1; off < 256; off <<= 1) {
    int v = (t >= off) ? tmp[t - off] : 0;
    __syncthreads();
    tmp[t] += v;
    __syncthreads();
  }
  if (t < nb) boff[t] = tmp[t] - s;
}

__global__ __launch_bounds__(256) void scan3(int* __restrict__ out, const int* __restrict__ boff,
                                             int* __restrict__ cur, int n) {
  int i = blockIdx.x * 256 + threadIdx.x;
  if (i < n) {
    int v = out[i] + boff[i >> 10];
    out[i] = v;
    cur[i] = v;
  }
}

// ---------------- CSR fill ----------------
__global__ __launch_bounds__(256) void fill_kernel(const int* __restrict__ src,
                                                   const int* __restrict__ dst,
                                                   int* cur_in, int* cur_out,
                                                   int* __restrict__ csr_in_src,
                                                   int* __restrict__ csr_in_eid,
                                                   int* __restrict__ csr_out_dst, int E) {
  int i = blockIdx.x * 256 + threadIdx.x;
  if (i < E) {
    int s = src[i], d = dst[i];
    int p = atomicAdd(&cur_in[d], 1);
    csr_in_src[p] = s;
    csr_in_eid[p] = i;
    int q = atomicAdd(&cur_out[s], 1);
    csr_out_dst[q] = d;
  }
}

// ---------------- fp32 matmul: out[N,128] = A[N,128] @ W[128,128] ----------------
__global__ __launch_bounds__(256) void mm128(const float* __restrict__ A,
                                             const float* __restrict__ W,
                                             float* __restrict__ out, int nrows) {
  __shared__ float As[64][128];
  __shared__ float Ws[128][64];
  int r0 = blockIdx.x * 64;
  int cb = blockIdx.y * 64;
  int tid = threadIdx.x;

#pragma unroll
  for (int i = 0; i < 8; i++) {
    int v = tid + 256 * i;
    int k = v >> 4, c4 = (v & 15) << 2;
    *(float4*)(&Ws[k][c4]) = *(const float4*)(W + k * FDIM + cb + c4);
  }
#pragma unroll
  for (int i = 0; i < 8; i++) {
    int v = tid + 256 * i;
    int r = v >> 5, k4 = (v & 31) << 2;
    int row = r0 + r;
    float4 a;
    if (row < nrows) a = *(const float4*)(A + (size_t)row * FDIM + k4);
    else a = make_float4(0.f, 0.f, 0.f, 0.f);
    int swz = ((r >> 2) & 7) << 2;
    *(float4*)(&As[r][k4 ^ swz]) = a;
  }
  __syncthreads();

  int tx = tid & 15, ty = tid >> 4;
  int rbase = ty * 4;
  int swz = (ty & 7) << 2;
  float acc[4][4] = {};
#pragma unroll 8
  for (int k = 0; k < 128; k++) {
    int kx = k ^ swz;
    float a0 = As[rbase + 0][kx];
    float a1 = As[rbase + 1][kx];
    float a2 = As[rbase + 2][kx];
    float a3 = As[rbase + 3][kx];
    float4 w = *(float4*)(&Ws[k][tx * 4]);
    acc[0][0] += a0 * w.x; acc[0][1] += a0 * w.y; acc[0][2] += a0 * w.z; acc[0][3] += a0 * w.w;
    acc[1][0] += a1 * w.x; acc[1][1] += a1 * w.y; acc[1][2] += a1 * w.z; acc[1][3] += a1 * w.w;
    acc[2][0] += a2 * w.x; acc[2][1] += a2 * w.y; acc[2][2] += a2 * w.z; acc[2][3] += a2 * w.w;
    acc[3][0] += a3 * w.x; acc[3][1] += a3 * w.y; acc[3][2] += a3 * w.z; acc[3][3] += a3 * w.w;
  }
#pragma unroll
  for (int rr = 0; rr < 4; rr++) {
    int row = r0 + rbase + rr;
    if (row < nrows) {
      float4 o = make_float4(acc[rr][0], acc[rr][1], acc[rr][2], acc[rr][3]);
      *(float4*)(out + (size_t)row * FDIM + cb + tx * 4) = o;
    }
  }
}

// ---------------- GCN aggregation: float4 gather, 32 lanes/node, unroll-4 MLP ----------------
__global__ __launch_bounds__(128) void gcn_gather4(const float4* __restrict__ tin,
                                                   const float4* __restrict__ tout,
                                                   const int* __restrict__ rp_in,
                                                   const int* __restrict__ deg_in,
                                                   const int* __restrict__ adj_in,
                                                   const int* __restrict__ rp_out,
                                                   const int* __restrict__ deg_out,
                                                   const int* __restrict__ adj_out,
                                                   const float* __restrict__ dinv_in,
                                                   const float* __restrict__ dinv_out,
                                                   const float* __restrict__ bin,
                                                   const float* __restrict__ bout,
                                                   float4* __restrict__ outp, int N) {
  int grp = threadIdx.x >> 5, lane = threadIdx.x & 31;
  int d = blockIdx.x * 4 + grp;
  if (d >= N) return;
  float wi = 0.5f * dinv_in[d], wo = 0.5f * dinv_out[d];
  float4 a0 = make_float4(0.f, 0.f, 0.f, 0.f);
  float4 a1 = a0, a2 = a0, a3 = a0;

  int p = rp_in[d], n1 = deg_in[d];
  int k = 0;
  for (; k + 4 <= n1; k += 4) {
    int s0 = adj_in[p + k], s1 = adj_in[p + k + 1], s2 = adj_in[p + k + 2], s3 = adj_in[p + k + 3];
    float w0 = wi * dinv_in[s0], w1 = wi * dinv_in[s1], w2 = wi * dinv_in[s2], w3 = wi * dinv_in[s3];
    float4 v0 = tin[(size_t)s0 * 32 + lane];
    float4 v1 = tin[(size_t)s1 * 32 + lane];
    float4 v2 = tin[(size_t)s2 * 32 + lane];
    float4 v3 = tin[(size_t)s3 * 32 + lane];
    a0.x += w0 * v0.x; a0.y += w0 * v0.y; a0.z += w0 * v0.z; a0.w += w0 * v0.w;
    a1.x += w1 * v1.x; a1.y += w1 * v1.y; a1.z += w1 * v1.z; a1.w += w1 * v1.w;
    a2.x += w2 * v2.x; a2.y += w2 * v2.y; a2.z += w2 * v2.z; a2.w += w2 * v2.w;
    a3.x += w3 * v3.x; a3.y += w3 * v3.y; a3.z += w3 * v3.z; a3.w += w3 * v3.w;
  }
  for (; k < n1; k++) {
    int s = adj_in[p + k];
    float w = wi * dinv_in[s];
    float4 v = tin[(size_t)s * 32 + lane];
    a0.x += w * v.x; a0.y += w * v.y; a0.z += w * v.z; a0.w += w * v.w;
  }

  int q = rp_out[d], n2 = deg_out[d];
  k = 0;
  for (; k + 4 <= n2; k += 4) {
    int s0 = adj_out[q + k], s1 = adj_out[q + k + 1], s2 = adj_out[q + k + 2], s3 = adj_out[q + k + 3];
    float w0 = wo * dinv_out[s0], w1 = wo * dinv_out[s1], w2 = wo * dinv_out[s2], w3 = wo * dinv_out[s3];
    float4 v0 = tout[(size_t)s0 * 32 + lane];
    float4 v1 = tout[(size_t)s1 * 32 + lane];
    float4 v2 = tout[(size_t)s2 * 32 + lane];
    float4 v3 = tout[(size_t)s3 * 32 + lane];
    a0.x += w0 * v0.x; a0.y += w0 * v0.y; a0.z += w0 * v0.z; a0.w += w0 * v0.w;
    a1.x += w1 * v1.x; a1.y += w1 * v1.y; a1.z += w1 * v1.z; a1.w += w1 * v1.w;
    a2.x += w2 * v2.x; a2.y += w2 * v2.y; a2.z += w2 * v2.z; a2.w += w2 * v2.w;
    a3.x += w3 * v3.x; a3.y += w3 * v3.y; a3.z += w3 * v3.z; a3.w += w3 * v3.w;
  }
  for (; k < n2; k++) {
    int s = adj_out[q + k];
    float w = wo * dinv_out[s];
    float4 v = tout[(size_t)s * 32 + lane];
    a0.x += w * v.x; a0.y += w * v.y; a0.z += w * v.z; a0.w += w * v.w;
  }

  float4 acc;
  acc.x = (a0.x + a1.x) + (a2.x + a3.x);
  acc.y = (a0.y + a1.y) + (a2.y + a3.y);
  acc.z = (a0.z + a1.z) + (a2.z + a3.z);
  acc.w = (a0.w + a1.w) + (a2.w + a3.w);

  const float4* b1 = (const float4*)bin;
  const float4* b2 = (const float4*)bout;
  float4 ba = b1[lane], bb = b2[lane];
  float4 o;
  o.x = acc.x + 0.5f * (ba.x + bb.x);
  o.y = acc.y + 0.5f * (ba.y + bb.y);
  o.z = acc.z + 0.5f * (ba.z + bb.z);
  o.w = acc.w + 0.5f * (ba.w + bb.w);
  o.x = o.x > 0.f ? o.x : 0.f;
  o.y = o.y > 0.f ? o.y : 0.f;
  o.z = o.z > 0.f ? o.z : 0.f;
  o.w = o.w > 0.f ? o.w : 0.f;
  outp[(size_t)d * 32 + lane] = o;
}

// ---------------- GATv2: fused online-softmax, 32 lanes/node, float4, unroll-2 ----------------
__global__ __launch_bounds__(128) void gat_fused2(const float4* __restrict__ gl,
                                                  const float4* __restrict__ gr,
                                                  const int* __restrict__ rp,
                                                  const int* __restrict__ deg,
                                                  const int* __restrict__ adj_src,
                                                  const int* __restrict__ adj_eid,
                                                  const float* __restrict__ eattr,
                                                  const float* __restrict__ we,
                                                  const float* __restrict__ att,
                                                  const float* __restrict__ gatb,
                                                  float4* __restrict__ outp, int N) {
  int grp = threadIdx.x >> 5, lane = threadIdx.x & 31;
  int d = blockIdx.x * 4 + grp;
  if (d >= N) return;

  float4 grv = gr[(size_t)d * 32 + lane];
  float4 wev = ((const float4*)we)[lane];
  float4 atv = ((const float4*)att)[lane];

  int p = rp[d], n1 = deg[d];
  float m = -1e30f, den = 0.f;
  float4 o = make_float4(0.f, 0.f, 0.f, 0.f);

#define GAT_LOGIT(g4, ea, pv)                                                     \
  {                                                                               \
    float vx = g4.x + grv.x + (ea) * wev.x; vx = vx > 0.f ? vx : 0.2f * vx;       \
    float vy = g4.y + grv.y + (ea) * wev.y; vy = vy > 0.f ? vy : 0.2f * vy;       \
    float vz = g4.z + grv.z + (ea) * wev.z; vz = vz > 0.f ? vz : 0.2f * vz;       \
    float vw = g4.w + grv.w + (ea) * wev.w; vw = vw > 0.f ? vw : 0.2f * vw;       \
    pv = vx * atv.x + vy * atv.y + vz * atv.z + vw * atv.w;                       \
    pv += __shfl_xor(pv, 1);                                                      \
    pv += __shfl_xor(pv, 2);                                                      \
    pv += __shfl_xor(pv, 4);                                                      \
  }

#define GAT_UPDATE(g4, pv)                                                        \
  {                                                                               \
    float mn = fmaxf(m, pv);                                                      \
    float sc = expf(m - mn);                                                      \
    float w = expf(pv - mn);                                                      \
    den = den * sc + w;                                                           \
    o.x = o.x * sc + w * g4.x;                                                    \
    o.y = o.y * sc + w * g4.y;                                                    \
    o.z = o.z * sc + w * g4.z;                                                    \
    o.w = o.w * sc + w * g4.w;                                                    \
    m = mn;                                                                       \
  }

  int k = 0;
  for (; k + 2 <= n1; k += 2) {
    int s0 = adj_src[p + k], s1 = adj_src[p + k + 1];
    int e0 = adj_eid[p + k], e1 = adj_eid[p + k + 1];
    float ea0 = eattr[e0], ea1 = eattr[e1];
    float4 g0 = gl[(size_t)s0 * 32 + lane];
    float4 g1 = gl[(size_t)s1 * 32 + lane];
    float pv0, pv1;
    GAT_LOGIT(g0, ea0, pv0);
    GAT_LOGIT(g1, ea1, pv1);
    GAT_UPDATE(g0, pv0);
    GAT_UPDATE(g1, pv1);
  }
  if (k < n1) {
    int s = adj_src[p + k], e = adj_eid[p + k];
    float ea = eattr[e];
    float4 g = gl[(size_t)s * 32 + lane];
    float pv;
    GAT_LOGIT(g, ea, pv);
    GAT_UPDATE(g, pv);
  }
  {  // self loop: s = d, ea = 1.0
    float4 g = gl[(size_t)d * 32 + lane];
    float pv;
    GAT_LOGIT(g, 1.0f, pv);
    GAT_UPDATE(g, pv);
  }
#undef GAT_LOGIT
#undef GAT_UPDATE

  float4 bb = ((const float4*)gatb)[lane];
  float4 r;
  r.x = o.x / den + bb.x;
  r.y = o.y / den + bb.y;
  r.z = o.z / den + bb.z;
  r.w = o.w / den + bb.w;
  outp[(size_t)d * 32 + lane] = r;
}

// ---------------- mean pool (batch sorted: running-sum per contiguous chunk) ----------------
__global__ __launch_bounds__(128) void pool_kernel(const float* __restrict__ srcf,
                                                   const int* __restrict__ batch,
                                                   float* __restrict__ zb,
                                                   int colOff, int N) {
  __shared__ int sb[PCH];
  int c0 = blockIdx.x * PCH;
  int t = threadIdx.x;
  int nmax = N - c0; if (nmax > PCH) nmax = PCH;
  for (int i = t; i < nmax; i += 128) sb[i] = batch[c0 + i];
  __syncthreads();
  float run = 0.f;
  int gp = sb[0];
  for (int i = 0; i < nmax; i++) {
    int g = sb[i];
    if (g != gp) {
      atomicAdd(&zb[(size_t)gp * 256 + colOff + t], run);
      run = 0.f; gp = g;
    }
    run += srcf[(size_t)(c0 + i) * FDIM + t];
  }
  atomicAdd(&zb[(size_t)gp * 256 + colOff + t], run);
}

// ---------------- head ----------------
__global__ __launch_bounds__(128) void head_kernel(const float* __restrict__ zb,
                                                   const float* __restrict__ cnt,
                                                   const float* __restrict__ w1,
                                                   const float* __restrict__ b1,
                                                   const float* __restrict__ w2,
                                                   const float* __restrict__ b2,
                                                   float* __restrict__ out, int G) {
  __shared__ float z[256];
  __shared__ float y[128];
  int g = blockIdx.x, t = threadIdx.x;
  float c = cnt[g];
  float cm = c > 1.f ? c : 1.f;
  z[t]       = zb[(size_t)g * 256 + t] / cm;
  z[t + 128] = zb[(size_t)g * 256 + 128 + t] / cm;
  __syncthreads();
  float acc = b1[t];
  for (int k = 0; k < 256; k++) acc += z[k] * w1[k * 128 + t];
  y[t] = acc > 0.f ? acc : 0.f;
  __syncthreads();
  if (t < 2) {
    float o = b2[t];
    for (int j = 0; j < 128; j++) o += y[j] * w2[j * 2 + t];
    out[(size_t)g * 2 + t] = o;
  }
}

extern "C" void kernel_launch(void* const* d_in, const int* in_sizes, int n_in,
                              void* d_out, int out_size, void* d_ws, size_t ws_size,
                              hipStream_t stream) {
  const float* x     = (const float*)d_in[0];
  const int*   ei    = (const int*)d_in[1];
  const float* eattr = (const float*)d_in[2];
  const int*   batch = (const int*)d_in[3];
  const float* dwi   = (const float*)d_in[4];
  const float* dbi   = (const float*)d_in[5];
  const float* dwo   = (const float*)d_in[6];
  const float* dbo   = (const float*)d_in[7];
  const float* wl    = (const float*)d_in[8];
  const float* wr    = (const float*)d_in[9];
  const float* we    = (const float*)d_in[10];
  const float* att   = (const float*)d_in[11];
  const float* gatb  = (const float*)d_in[12];
  const float* w1    = (const float*)d_in[13];
  const float* b1    = (const float*)d_in[14];
  const float* w2    = (const float*)d_in[15];
  const float* b2    = (const float*)d_in[16];

  int N = in_sizes[0] / FDIM;
  int E = in_sizes[1] / 2;
  int G = out_size / 2;
  const int* src = ei;
  const int* dst = ei + E;

  // ---- workspace layout (4-byte elements) ----
  float* ws = (float*)d_ws;
  size_t off = 0;
  float* A        = ws + off; off += (size_t)N * FDIM;
  float* B        = ws + off; off += (size_t)N * FDIM;
  float* C        = ws + off; off += (size_t)N * FDIM;
  float* dinv2    = ws + off; off += 2 * (size_t)N;          // [dinv_in | dinv_out]
  int* deg2       = (int*)(ws + off); off += 2 * (size_t)N;  // [deg_in | deg_out]
  int* rp_in      = (int*)(ws + off); off += (size_t)N;
  int* rp_out     = (int*)(ws + off); off += (size_t)N;
  int* cur_in     = (int*)(ws + off); off += (size_t)N;
  int* cur_out    = (int*)(ws + off); off += (size_t)N;
  int* csr_in_src = (int*)(ws + off); off += (size_t)E;
  int* csr_in_eid = (int*)(ws + off); off += (size_t)E;
  int* csr_out_dst= (int*)(ws + off); off += (size_t)E;
  int* bsums      = (int*)(ws + off); off += 256;
  int* boff       = (int*)(ws + off); off += 256;
  float* zb       = ws + off; off += (size_t)G * 256;
  float* cnt      = ws + off; off += (size_t)G;

  int* deg_in = deg2, *deg_out = deg2 + N;
  float* dinv_in = dinv2, *dinv_out = dinv2 + N;

  dim3 mmg(cdiv(N, 64), 2);
  int nb1 = cdiv(N, 1024);

  // ---- CSR build ----
  hipMemsetAsync(deg2, 0, 2 * (size_t)N * sizeof(int), stream);
  degi_kernel<<<cdiv(E, 256), 256, 0, stream>>>(src, dst, deg_in, deg_out, E);
  dinv2_kernel<<<cdiv(2LL * N, 256), 256, 0, stream>>>(deg2, dinv2, 2 * N);
  scan1<<<nb1, 256, 0, stream>>>(deg_in, rp_in, bsums, N);
  scan2<<<1, 256, 0, stream>>>(bsums, boff, nb1);
  scan3<<<cdiv(N, 256), 256, 0, stream>>>(rp_in, boff, cur_in, N);
  scan1<<<nb1, 256, 0, stream>>>(deg_out, rp_out, bsums, N);
  scan2<<<1, 256, 0, stream>>>(bsums, boff, nb1);
  scan3<<<cdiv(N, 256), 256, 0, stream>>>(rp_out, boff, cur_out, N);
  fill_kernel<<<cdiv(E, 256), 256, 0, stream>>>(src, dst, cur_in, cur_out,
                                                csr_in_src, csr_in_eid, csr_out_dst, E);

  // ---- pool counts (binary search over sorted batch; no atomics) ----
  hipMemsetAsync(zb, 0, (size_t)G * 256 * sizeof(float), stream);
  cnt_sorted<<<cdiv(G, 256), 256, 0, stream>>>(batch, cnt, N, G);

  // ---- DirGNN layer 0 (h = x) ----
  mm128<<<mmg, 256, 0, stream>>>(x, dwi, B, N);
  mm128<<<mmg, 256, 0, stream>>>(x, dwo, C, N);
  gcn_gather4<<<cdiv(N, 4), 128, 0, stream>>>((const float4*)B, (const float4*)C,
                                              rp_in, deg_in, csr_in_src,
                                              rp_out, deg_out, csr_out_dst,
                                              dinv_in, dinv_out, dbi, dbo, (float4*)A, N);
  // ---- DirGNN layer 1 (h = A) ----
  mm128<<<mmg, 256, 0, stream>>>(A, dwi + 16384, B, N);
  mm128<<<mmg, 256, 0, stream>>>(A, dwo + 16384, C, N);
  gcn_gather4<<<cdiv(N, 4), 128, 0, stream>>>((const float4*)B, (const float4*)C,
                                              rp_in, deg_in, csr_in_src,
                                              rp_out, deg_out, csr_out_dst,
                                              dinv_in, dinv_out, dbi + 128, dbo + 128, (float4*)A, N);
  // pool x1 -> zb[:, 0:128]
  pool_kernel<<<cdiv(N, PCH), 128, 0, stream>>>(A, batch, zb, 0, N);

  // ---- GATv2 branch (on original x) ----
  mm128<<<mmg, 256, 0, stream>>>(x, wl, B, N);   // gl (source transform)
  mm128<<<mmg, 256, 0, stream>>>(x, wr, C, N);   // gr (target transform)
  gat_fused2<<<cdiv(N, 4), 128, 0, stream>>>((const float4*)B, (const float4*)C,
                                             rp_in, deg_in, csr_in_src, csr_in_eid,
                                             eattr, we, att, gatb, (float4*)A, N);
  // pool x2 -> zb[:, 128:256]
  pool_kernel<<<cdiv(N, PCH), 128, 0, stream>>>(A, batch, zb, 128, N);

  // head
  head_kernel<<<G, 128, 0, stream>>>(zb, cnt, w1, b1, w2, b2, (float*)d_out, G);
}

// Round 6
// 1245.111 us; speedup vs baseline: 2.6725x; 1.0705x over previous
//
#include <hip/hip_runtime.h>
#include <cstdint>

#define FDIM 128
#define PCH 64

static inline int cdiv(long long a, long long b) { return (int)((a + b - 1) / b); }

// ---------------- degree histograms (int) ----------------
__global__ __launch_bounds__(256) void degi_kernel(const int* __restrict__ src,
                                                   const int* __restrict__ dst,
                                                   int* deg_in, int* deg_out, int E) {
  int i = blockIdx.x * 256 + threadIdx.x;
  if (i < E) {
    atomicAdd(&deg_in[dst[i]], 1);
    atomicAdd(&deg_out[src[i]], 1);
  }
}

// dinv[i] = deg>0 ? 1/sqrt(deg) : 0
__global__ __launch_bounds__(256) void dinv2_kernel(const int* __restrict__ degs,
                                                    float* __restrict__ dinv, int n2) {
  int i = blockIdx.x * 256 + threadIdx.x;
  if (i < n2) {
    int v = degs[i];
    dinv[i] = v > 0 ? 1.0f / sqrtf((float)v) : 0.f;
  }
}

// batch is sorted: cnt[g] = upper_bound(g) - lower_bound(g). No atomics.
__global__ __launch_bounds__(256) void cnt_sorted(const int* __restrict__ batch,
                                                  float* __restrict__ cnt, int N, int G) {
  int g = blockIdx.x * 256 + threadIdx.x;
  if (g >= G) return;
  int lo = 0, hi = N;
  while (lo < hi) { int mid = (lo + hi) >> 1; if (batch[mid] < g) lo = mid + 1; else hi = mid; }
  int lo2 = lo, hi2 = N;
  while (lo2 < hi2) { int mid = (lo2 + hi2) >> 1; if (batch[mid] <= g) lo2 = mid + 1; else hi2 = mid; }
  cnt[g] = (float)(lo2 - lo);
}

// ---------------- hierarchical exclusive scan (n <= 256*1024) ----------------
__global__ __launch_bounds__(256) void scan1(const int* __restrict__ in, int* __restrict__ out,
                                             int* __restrict__ bsums, int n) {
  __shared__ int tmp[256];
  int t = threadIdx.x;
  int base = blockIdx.x * 1024 + t * 4;
  int a[4];
#pragma unroll
  for (int j = 0; j < 4; j++) a[j] = (base + j < n) ? in[base + j] : 0;
  int s = a[0] + a[1] + a[2] + a[3];
  tmp[t] = s;
  __syncthreads();
  for (int off = 1; off < 256; off <<= 1) {
    int v = (t >= off) ? tmp[t - off] : 0;
    __syncthreads();
    tmp[t] += v;
    __syncthreads();
  }
  int excl = tmp[t] - s;
  int run = excl;
#pragma unroll
  for (int j = 0; j < 4; j++) {
    if (base + j < n) out[base + j] = run;
    run += a[j];
  }
  if (t == 255) bsums[blockIdx.x] = tmp[255];
}

__global__ __launch_bounds__(256) void scan2(const int* __restrict__ bsums,
                                             int* __restrict__ boff, int nb) {
  __shared__ int tmp[256];
  int t = threadIdx.x;
  int s = (t < nb) ? bsums[t] : 0;
  tmp[t] = s;
  __syncthreads();
  for (int off = 1; off < 256; off <<= 1) {
    int v = (t >= off) ? tmp[t - off] : 0;
    __syncthreads();
    tmp[t] += v;
    __syncthreads();
  }
  if (t < nb) boff[t] = tmp[t] - s;
}

__global__ __launch_bounds__(256) void scan3(int* __restrict__ out, const int* __restrict__ boff,
                                             int* __restrict__ cur, int n) {
  int i = blockIdx.x * 256 + threadIdx.x;
  if (i < n) {
    int v = out[i] + boff[i >> 10];
    out[i] = v;
    cur[i] = v;
  }
}

// ---------------- CSR fill: packed {src, eattr_bits} int2 for in-CSR ----------------
__global__ __launch_bounds__(256) void fill_kernel(const int* __restrict__ src,
                                                   const int* __restrict__ dst,
                                                   const float* __restrict__ eattr,
                                                   int* cur_in, int* cur_out,
                                                   int2* __restrict__ csr_in,
                                                   int* __restrict__ csr_out_dst, int E) {
  int i = blockIdx.x * 256 + threadIdx.x;
  if (i < E) {
    int s = src[i], d = dst[i];
    float ea = eattr[i];
    int p = atomicAdd(&cur_in[d], 1);
    csr_in[p] = make_int2(s, __float_as_int(ea));
    int q = atomicAdd(&cur_out[s], 1);
    csr_out_dst[q] = d;
  }
}

// ---------------- fp32 matmul: out[N,128] = A[N,128] @ W[128,128] ----------------
// 64-row full-width tile: A staged once, two passes over W column halves.
__global__ __launch_bounds__(256) void mm128f(const float* __restrict__ A,
                                              const float* __restrict__ W,
                                              float* __restrict__ out, int nrows) {
  __shared__ float As[64][128];   // [r][k], swizzled columns
  __shared__ float Ws[128][64];   // [k][c] for the current column half
  int r0 = blockIdx.x * 64;
  int tid = threadIdx.x;

#pragma unroll
  for (int i = 0; i < 8; i++) {
    int v = tid + 256 * i;          // float4 index into 64x128 A tile
    int r = v >> 5, k4 = (v & 31) << 2;
    int row = r0 + r;
    float4 a;
    if (row < nrows) a = *(const float4*)(A + (size_t)row * FDIM + k4);
    else a = make_float4(0.f, 0.f, 0.f, 0.f);
    int swz = ((r >> 2) & 7) << 2;
    *(float4*)(&As[r][k4 ^ swz]) = a;
  }

  int tx = tid & 15, ty = tid >> 4;
  int rbase = ty * 4;
  int swz = (ty & 7) << 2;
  float acc[2][4][4] = {};

#pragma unroll
  for (int half = 0; half < 2; half++) {
    if (half) __syncthreads();  // previous compute done reading Ws
    int cb = half * 64;
#pragma unroll
    for (int i = 0; i < 8; i++) {
      int v = tid + 256 * i;        // float4 index into 128x64 W tile
      int k = v >> 4, c4 = (v & 15) << 2;
      *(float4*)(&Ws[k][c4]) = *(const float4*)(W + k * FDIM + cb + c4);
    }
    __syncthreads();

#pragma unroll 8
    for (int k = 0; k < 128; k++) {
      int kx = k ^ swz;
      float a0 = As[rbase + 0][kx];
      float a1 = As[rbase + 1][kx];
      float a2 = As[rbase + 2][kx];
      float a3 = As[rbase + 3][kx];
      float4 w = *(float4*)(&Ws[k][tx * 4]);
      acc[half][0][0] += a0 * w.x; acc[half][0][1] += a0 * w.y; acc[half][0][2] += a0 * w.z; acc[half][0][3] += a0 * w.w;
      acc[half][1][0] += a1 * w.x; acc[half][1][1] += a1 * w.y; acc[half][1][2] += a1 * w.z; acc[half][1][3] += a1 * w.w;
      acc[half][2][0] += a2 * w.x; acc[half][2][1] += a2 * w.y; acc[half][2][2] += a2 * w.z; acc[half][2][3] += a2 * w.w;
      acc[half][3][0] += a3 * w.x; acc[half][3][1] += a3 * w.y; acc[half][3][2] += a3 * w.z; acc[half][3][3] += a3 * w.w;
    }
  }

#pragma unroll
  for (int half = 0; half < 2; half++) {
#pragma unroll
    for (int rr = 0; rr < 4; rr++) {
      int row = r0 + rbase + rr;
      if (row < nrows) {
        float4 o = make_float4(acc[half][rr][0], acc[half][rr][1], acc[half][rr][2], acc[half][rr][3]);
        *(float4*)(out + (size_t)row * FDIM + half * 64 + tx * 4) = o;
      }
    }
  }
}

// ---------------- GCN aggregation: float4 gather, 32 lanes/node, unroll-4 MLP ----------------
__global__ __launch_bounds__(128) void gcn_gather4(const float4* __restrict__ tin,
                                                   const float4* __restrict__ tout,
                                                   const int* __restrict__ rp_in,
                                                   const int* __restrict__ deg_in,
                                                   const int2* __restrict__ adj_in,
                                                   const int* __restrict__ rp_out,
                                                   const int* __restrict__ deg_out,
                                                   const int* __restrict__ adj_out,
                                                   const float* __restrict__ dinv_in,
                                                   const float* __restrict__ dinv_out,
                                                   const float* __restrict__ bin,
                                                   const float* __restrict__ bout,
                                                   float4* __restrict__ outp, int N) {
  int grp = threadIdx.x >> 5, lane = threadIdx.x & 31;
  int d = blockIdx.x * 4 + grp;
  if (d >= N) return;
  float wi = 0.5f * dinv_in[d], wo = 0.5f * dinv_out[d];
  float4 a0 = make_float4(0.f, 0.f, 0.f, 0.f);
  float4 a1 = a0, a2 = a0, a3 = a0;

  int p = rp_in[d], n1 = deg_in[d];
  int k = 0;
  for (; k + 4 <= n1; k += 4) {
    int s0 = adj_in[p + k].x, s1 = adj_in[p + k + 1].x, s2 = adj_in[p + k + 2].x, s3 = adj_in[p + k + 3].x;
    float w0 = wi * dinv_in[s0], w1 = wi * dinv_in[s1], w2 = wi * dinv_in[s2], w3 = wi * dinv_in[s3];
    float4 v0 = tin[(size_t)s0 * 32 + lane];
    float4 v1 = tin[(size_t)s1 * 32 + lane];
    float4 v2 = tin[(size_t)s2 * 32 + lane];
    float4 v3 = tin[(size_t)s3 * 32 + lane];
    a0.x += w0 * v0.x; a0.y += w0 * v0.y; a0.z += w0 * v0.z; a0.w += w0 * v0.w;
    a1.x += w1 * v1.x; a1.y += w1 * v1.y; a1.z += w1 * v1.z; a1.w += w1 * v1.w;
    a2.x += w2 * v2.x; a2.y += w2 * v2.y; a2.z += w2 * v2.z; a2.w += w2 * v2.w;
    a3.x += w3 * v3.x; a3.y += w3 * v3.y; a3.z += w3 * v3.z; a3.w += w3 * v3.w;
  }
  for (; k < n1; k++) {
    int s = adj_in[p + k].x;
    float w = wi * dinv_in[s];
    float4 v = tin[(size_t)s * 32 + lane];
    a0.x += w * v.x; a0.y += w * v.y; a0.z += w * v.z; a0.w += w * v.w;
  }

  int q = rp_out[d], n2 = deg_out[d];
  k = 0;
  for (; k + 4 <= n2; k += 4) {
    int s0 = adj_out[q + k], s1 = adj_out[q + k + 1], s2 = adj_out[q + k + 2], s3 = adj_out[q + k + 3];
    float w0 = wo * dinv_out[s0], w1 = wo * dinv_out[s1], w2 = wo * dinv_out[s2], w3 = wo * dinv_out[s3];
    float4 v0 = tout[(size_t)s0 * 32 + lane];
    float4 v1 = tout[(size_t)s1 * 32 + lane];
    float4 v2 = tout[(size_t)s2 * 32 + lane];
    float4 v3 = tout[(size_t)s3 * 32 + lane];
    a0.x += w0 * v0.x; a0.y += w0 * v0.y; a0.z += w0 * v0.z; a0.w += w0 * v0.w;
    a1.x += w1 * v1.x; a1.y += w1 * v1.y; a1.z += w1 * v1.z; a1.w += w1 * v1.w;
    a2.x += w2 * v2.x; a2.y += w2 * v2.y; a2.z += w2 * v2.z; a2.w += w2 * v2.w;
    a3.x += w3 * v3.x; a3.y += w3 * v3.y; a3.z += w3 * v3.z; a3.w += w3 * v3.w;
  }
  for (; k < n2; k++) {
    int s = adj_out[q + k];
    float w = wo * dinv_out[s];
    float4 v = tout[(size_t)s * 32 + lane];
    a0.x += w * v.x; a0.y += w * v.y; a0.z += w * v.z; a0.w += w * v.w;
  }

  float4 acc;
  acc.x = (a0.x + a1.x) + (a2.x + a3.x);
  acc.y = (a0.y + a1.y) + (a2.y + a3.y);
  acc.z = (a0.z + a1.z) + (a2.z + a3.z);
  acc.w = (a0.w + a1.w) + (a2.w + a3.w);

  const float4* b1 = (const float4*)bin;
  const float4* b2 = (const float4*)bout;
  float4 ba = b1[lane], bb = b2[lane];
  float4 o;
  o.x = acc.x + 0.5f * (ba.x + bb.x);
  o.y = acc.y + 0.5f * (ba.y + bb.y);
  o.z = acc.z + 0.5f * (ba.z + bb.z);
  o.w = acc.w + 0.5f * (ba.w + bb.w);
  o.x = o.x > 0.f ? o.x : 0.f;
  o.y = o.y > 0.f ? o.y : 0.f;
  o.z = o.z > 0.f ? o.z : 0.f;
  o.w = o.w > 0.f ? o.w : 0.f;
  outp[(size_t)d * 32 + lane] = o;
}

// ---------------- GATv2: fused online-softmax, 32 lanes/node, float4, unroll-2 ----------------
__global__ __launch_bounds__(128) void gat_fused2(const float4* __restrict__ gl,
                                                  const float4* __restrict__ gr,
                                                  const int* __restrict__ rp,
                                                  const int* __restrict__ deg,
                                                  const int2* __restrict__ adj,
                                                  const float* __restrict__ we,
                                                  const float* __restrict__ att,
                                                  const float* __restrict__ gatb,
                                                  float4* __restrict__ outp, int N) {
  int grp = threadIdx.x >> 5, lane = threadIdx.x & 31;
  int d = blockIdx.x * 4 + grp;
  if (d >= N) return;

  float4 grv = gr[(size_t)d * 32 + lane];
  float4 wev = ((const float4*)we)[lane];
  float4 atv = ((const float4*)att)[lane];

  int p = rp[d], n1 = deg[d];
  float m = -1e30f, den = 0.f;
  float4 o = make_float4(0.f, 0.f, 0.f, 0.f);

#define GAT_LOGIT(g4, ea, pv)                                                     \
  {                                                                               \
    float vx = g4.x + grv.x + (ea) * wev.x; vx = vx > 0.f ? vx : 0.2f * vx;       \
    float vy = g4.y + grv.y + (ea) * wev.y; vy = vy > 0.f ? vy : 0.2f * vy;       \
    float vz = g4.z + grv.z + (ea) * wev.z; vz = vz > 0.f ? vz : 0.2f * vz;       \
    float vw = g4.w + grv.w + (ea) * wev.w; vw = vw > 0.f ? vw : 0.2f * vw;       \
    pv = vx * atv.x + vy * atv.y + vz * atv.z + vw * atv.w;                       \
    pv += __shfl_xor(pv, 1);                                                      \
    pv += __shfl_xor(pv, 2);                                                      \
    pv += __shfl_xor(pv, 4);                                                      \
  }

#define GAT_UPDATE(g4, pv)                                                        \
  {                                                                               \
    float mn = fmaxf(m, pv);                                                      \
    float sc = expf(m - mn);                                                      \
    float w = expf(pv - mn);                                                      \
    den = den * sc + w;                                                           \
    o.x = o.x * sc + w * g4.x;                                                    \
    o.y = o.y * sc + w * g4.y;                                                    \
    o.z = o.z * sc + w * g4.z;                                                    \
    o.w = o.w * sc + w * g4.w;                                                    \
    m = mn;                                                                       \
  }

  int k = 0;
  for (; k + 2 <= n1; k += 2) {
    int2 e0 = adj[p + k], e1 = adj[p + k + 1];
    int s0 = e0.x, s1 = e1.x;
    float ea0 = __int_as_float(e0.y), ea1 = __int_as_float(e1.y);
    float4 g0 = gl[(size_t)s0 * 32 + lane];
    float4 g1 = gl[(size_t)s1 * 32 + lane];
    float pv0, pv1;
    GAT_LOGIT(g0, ea0, pv0);
    GAT_LOGIT(g1, ea1, pv1);
    GAT_UPDATE(g0, pv0);
    GAT_UPDATE(g1, pv1);
  }
  if (k < n1) {
    int2 e = adj[p + k];
    float ea = __int_as_float(e.y);
    float4 g = gl[(size_t)e.x * 32 + lane];
    float pv;
    GAT_LOGIT(g, ea, pv);
    GAT_UPDATE(g, pv);
  }
  {  // self loop: s = d, ea = 1.0
    float4 g = gl[(size_t)d * 32 + lane];
    float pv;
    GAT_LOGIT(g, 1.0f, pv);
    GAT_UPDATE(g, pv);
  }
#undef GAT_LOGIT
#undef GAT_UPDATE

  float4 bb = ((const float4*)gatb)[lane];
  float4 r;
  r.x = o.x / den + bb.x;
  r.y = o.y / den + bb.y;
  r.z = o.z / den + bb.z;
  r.w = o.w / den + bb.w;
  outp[(size_t)d * 32 + lane] = r;
}

// ---------------- mean pool (batch sorted: running-sum per contiguous chunk) ----------------
__global__ __launch_bounds__(128) void pool_kernel(const float* __restrict__ srcf,
                                                   const int* __restrict__ batch,
                                                   float* __restrict__ zb,
                                                   int colOff, int N) {
  __shared__ int sb[PCH];
  int c0 = blockIdx.x * PCH;
  int t = threadIdx.x;
  int nmax = N - c0; if (nmax > PCH) nmax = PCH;
  if (t < nmax) sb[t] = batch[c0 + t];
  __syncthreads();
  float run = 0.f;
  int gp = sb[0];
  for (int i = 0; i < nmax; i++) {
    int g = sb[i];
    if (g != gp) {
      atomicAdd(&zb[(size_t)gp * 256 + colOff + t], run);
      run = 0.f; gp = g;
    }
    run += srcf[(size_t)(c0 + i) * FDIM + t];
  }
  atomicAdd(&zb[(size_t)gp * 256 + colOff + t], run);
}

// ---------------- head ----------------
__global__ __launch_bounds__(128) void head_kernel(const float* __restrict__ zb,
                                                   const float* __restrict__ cnt,
                                                   const float* __restrict__ w1,
                                                   const float* __restrict__ b1,
                                                   const float* __restrict__ w2,
                                                   const float* __restrict__ b2,
                                                   float* __restrict__ out, int G) {
  __shared__ float z[256];
  __shared__ float y[128];
  int g = blockIdx.x, t = threadIdx.x;
  float c = cnt[g];
  float cm = c > 1.f ? c : 1.f;
  z[t]       = zb[(size_t)g * 256 + t] / cm;
  z[t + 128] = zb[(size_t)g * 256 + 128 + t] / cm;
  __syncthreads();
  float acc = b1[t];
  for (int k = 0; k < 256; k++) acc += z[k] * w1[k * 128 + t];
  y[t] = acc > 0.f ? acc : 0.f;
  __syncthreads();
  if (t < 2) {
    float o = b2[t];
    for (int j = 0; j < 128; j++) o += y[j] * w2[j * 2 + t];
    out[(size_t)g * 2 + t] = o;
  }
}

extern "C" void kernel_launch(void* const* d_in, const int* in_sizes, int n_in,
                              void* d_out, int out_size, void* d_ws, size_t ws_size,
                              hipStream_t stream) {
  const float* x     = (const float*)d_in[0];
  const int*   ei    = (const int*)d_in[1];
  const float* eattr = (const float*)d_in[2];
  const int*   batch = (const int*)d_in[3];
  const float* dwi   = (const float*)d_in[4];
  const float* dbi   = (const float*)d_in[5];
  const float* dwo   = (const float*)d_in[6];
  const float* dbo   = (const float*)d_in[7];
  const float* wl    = (const float*)d_in[8];
  const float* wr    = (const float*)d_in[9];
  const float* we    = (const float*)d_in[10];
  const float* att   = (const float*)d_in[11];
  const float* gatb  = (const float*)d_in[12];
  const float* w1    = (const float*)d_in[13];
  const float* b1    = (const float*)d_in[14];
  const float* w2    = (const float*)d_in[15];
  const float* b2    = (const float*)d_in[16];

  int N = in_sizes[0] / FDIM;
  int E = in_sizes[1] / 2;
  int G = out_size / 2;
  const int* src = ei;
  const int* dst = ei + E;

  // ---- workspace layout (4-byte elements; keep int2 regions 8B-aligned) ----
  float* ws = (float*)d_ws;
  size_t off = 0;
  float* A        = ws + off; off += (size_t)N * FDIM;
  float* B        = ws + off; off += (size_t)N * FDIM;
  float* C        = ws + off; off += (size_t)N * FDIM;
  float* dinv2    = ws + off; off += 2 * (size_t)N;          // [dinv_in | dinv_out]
  int* deg2       = (int*)(ws + off); off += 2 * (size_t)N;  // [deg_in | deg_out]
  int* rp_in      = (int*)(ws + off); off += (size_t)N;
  int* rp_out     = (int*)(ws + off); off += (size_t)N;
  int* cur_in     = (int*)(ws + off); off += (size_t)N;
  int* cur_out    = (int*)(ws + off); off += (size_t)N;
  int2* csr_in    = (int2*)(ws + off); off += 2 * (size_t)E; // packed {src, eattr_bits}
  int* csr_out_dst= (int*)(ws + off); off += (size_t)E;
  int* bsums      = (int*)(ws + off); off += 256;
  int* boff       = (int*)(ws + off); off += 256;
  float* zb       = ws + off; off += (size_t)G * 256;
  float* cnt      = ws + off; off += (size_t)G;

  int* deg_in = deg2, *deg_out = deg2 + N;
  float* dinv_in = dinv2, *dinv_out = dinv2 + N;

  int nb1 = cdiv(N, 1024);

  // ---- CSR build ----
  hipMemsetAsync(deg2, 0, 2 * (size_t)N * sizeof(int), stream);
  degi_kernel<<<cdiv(E, 256), 256, 0, stream>>>(src, dst, deg_in, deg_out, E);
  dinv2_kernel<<<cdiv(2LL * N, 256), 256, 0, stream>>>(deg2, dinv2, 2 * N);
  scan1<<<nb1, 256, 0, stream>>>(deg_in, rp_in, bsums, N);
  scan2<<<1, 256, 0, stream>>>(bsums, boff, nb1);
  scan3<<<cdiv(N, 256), 256, 0, stream>>>(rp_in, boff, cur_in, N);
  scan1<<<nb1, 256, 0, stream>>>(deg_out, rp_out, bsums, N);
  scan2<<<1, 256, 0, stream>>>(bsums, boff, nb1);
  scan3<<<cdiv(N, 256), 256, 0, stream>>>(rp_out, boff, cur_out, N);
  fill_kernel<<<cdiv(E, 256), 256, 0, stream>>>(src, dst, eattr, cur_in, cur_out,
                                                csr_in, csr_out_dst, E);

  // ---- pool counts (binary search over sorted batch; no atomics) ----
  hipMemsetAsync(zb, 0, (size_t)G * 256 * sizeof(float), stream);
  cnt_sorted<<<cdiv(G, 256), 256, 0, stream>>>(batch, cnt, N, G);

  // ---- DirGNN layer 0 (h = x) ----
  mm128f<<<cdiv(N, 64), 256, 0, stream>>>(x, dwi, B, N);
  mm128f<<<cdiv(N, 64), 256, 0, stream>>>(x, dwo, C, N);
  gcn_gather4<<<cdiv(N, 4), 128, 0, stream>>>((const float4*)B, (const float4*)C,
                                              rp_in, deg_in, csr_in,
                                              rp_out, deg_out, csr_out_dst,
                                              dinv_in, dinv_out, dbi, dbo, (float4*)A, N);
  // ---- DirGNN layer 1 (h = A) ----
  mm128f<<<cdiv(N, 64), 256, 0, stream>>>(A, dwi + 16384, B, N);
  mm128f<<<cdiv(N, 64), 256, 0, stream>>>(A, dwo + 16384, C, N);
  gcn_gather4<<<cdiv(N, 4), 128, 0, stream>>>((const float4*)B, (const float4*)C,
                                              rp_in, deg_in, csr_in,
                                              rp_out, deg_out, csr_out_dst,
                                              dinv_in, dinv_out, dbi + 128, dbo + 128, (float4*)A, N);
  // pool x1 -> zb[:, 0:128]
  pool_kernel<<<cdiv(N, PCH), 128, 0, stream>>>(A, batch, zb, 0, N);

  // ---- GATv2 branch (on original x) ----
  mm128f<<<cdiv(N, 64), 256, 0, stream>>>(x, wl, B, N);   // gl (source transform)
  mm128f<<<cdiv(N, 64), 256, 0, stream>>>(x, wr, C, N);   // gr (target transform)
  gat_fused2<<<cdiv(N, 4), 128, 0, stream>>>((const float4*)B, (const float4*)C,
                                             rp_in, deg_in, csr_in,
                                             we, att, gatb, (float4*)A, N);
  // pool x2 -> zb[:, 128:256]
  pool_kernel<<<cdiv(N, PCH), 128, 0, stream>>>(A, batch, zb, 128, N);

  // head
  head_kernel<<<G, 128, 0, stream>>>(zb, cnt, w1, b1, w2, b2, (float*)d_out, G);
}

// Round 7
// 1206.615 us; speedup vs baseline: 2.7577x; 1.0319x over previous
//
#include <hip/hip_runtime.h>
#include <cstdint>

#define FDIM 128
#define PCH 64

static inline int cdiv(long long a, long long b) { return (int)((a + b - 1) / b); }

// ---------------- degree histograms (int), 4 edges/thread for MLP ----------------
__global__ __launch_bounds__(256) void degi_kernel(const int* __restrict__ src,
                                                   const int* __restrict__ dst,
                                                   int* __restrict__ deg_in,
                                                   int* __restrict__ deg_out, int E) {
  int base = (blockIdx.x * 256 + threadIdx.x) * 4;
  if (base + 4 <= E) {
    int4 s4 = *(const int4*)(src + base);
    int4 d4 = *(const int4*)(dst + base);
    atomicAdd(&deg_in[d4.x], 1);
    atomicAdd(&deg_in[d4.y], 1);
    atomicAdd(&deg_in[d4.z], 1);
    atomicAdd(&deg_in[d4.w], 1);
    atomicAdd(&deg_out[s4.x], 1);
    atomicAdd(&deg_out[s4.y], 1);
    atomicAdd(&deg_out[s4.z], 1);
    atomicAdd(&deg_out[s4.w], 1);
  } else {
    for (int i = base; i < E; i++) {
      atomicAdd(&deg_in[dst[i]], 1);
      atomicAdd(&deg_out[src[i]], 1);
    }
  }
}

// dinv[i] = deg>0 ? 1/sqrt(deg) : 0
__global__ __launch_bounds__(256) void dinv2_kernel(const int* __restrict__ degs,
                                                    float* __restrict__ dinv, int n2) {
  int i = blockIdx.x * 256 + threadIdx.x;
  if (i < n2) {
    int v = degs[i];
    dinv[i] = v > 0 ? 1.0f / sqrtf((float)v) : 0.f;
  }
}

// batch is sorted: cnt[g] = upper_bound(g) - lower_bound(g). No atomics.
__global__ __launch_bounds__(256) void cnt_sorted(const int* __restrict__ batch,
                                                  float* __restrict__ cnt, int N, int G) {
  int g = blockIdx.x * 256 + threadIdx.x;
  if (g >= G) return;
  int lo = 0, hi = N;
  while (lo < hi) { int mid = (lo + hi) >> 1; if (batch[mid] < g) lo = mid + 1; else hi = mid; }
  int lo2 = lo, hi2 = N;
  while (lo2 < hi2) { int mid = (lo2 + hi2) >> 1; if (batch[mid] <= g) lo2 = mid + 1; else hi2 = mid; }
  cnt[g] = (float)(lo2 - lo);
}

// ---------------- hierarchical exclusive scan (n <= 256*1024) ----------------
__global__ __launch_bounds__(256) void scan1(const int* __restrict__ in, int* __restrict__ out,
                                             int* __restrict__ bsums, int n) {
  __shared__ int tmp[256];
  int t = threadIdx.x;
  int base = blockIdx.x * 1024 + t * 4;
  int a[4];
#pragma unroll
  for (int j = 0; j < 4; j++) a[j] = (base + j < n) ? in[base + j] : 0;
  int s = a[0] + a[1] + a[2] + a[3];
  tmp[t] = s;
  __syncthreads();
  for (int off = 1; off < 256; off <<= 1) {
    int v = (t >= off) ? tmp[t - off] : 0;
    __syncthreads();
    tmp[t] += v;
    __syncthreads();
  }
  int excl = tmp[t] - s;
  int run = excl;
#pragma unroll
  for (int j = 0; j < 4; j++) {
    if (base + j < n) out[base + j] = run;
    run += a[j];
  }
  if (t == 255) bsums[blockIdx.x] = tmp[255];
}

__global__ __launch_bounds__(256) void scan2(const int* __restrict__ bsums,
                                             int* __restrict__ boff, int nb) {
  __shared__ int tmp[256];
  int t = threadIdx.x;
  int s = (t < nb) ? bsums[t] : 0;
  tmp[t] = s;
  __syncthreads();
  for (int off = 1; off < 256; off <<= 1) {
    int v = (t >= off) ? tmp[t - off] : 0;
    __syncthreads();
    tmp[t] += v;
    __syncthreads();
  }
  if (t < nb) boff[t] = tmp[t] - s;
}

__global__ __launch_bounds__(256) void scan3(int* __restrict__ out, const int* __restrict__ boff,
                                             int* __restrict__ cur, int n) {
  int i = blockIdx.x * 256 + threadIdx.x;
  if (i < n) {
    int v = out[i] + boff[i >> 10];
    out[i] = v;
    cur[i] = v;
  }
}

// ---------------- CSR fill: 4 edges/thread, atomics batched before stores ----------------
__global__ __launch_bounds__(256) void fill_kernel(const int* __restrict__ src,
                                                   const int* __restrict__ dst,
                                                   const float* __restrict__ eattr,
                                                   int* __restrict__ cur_in,
                                                   int* __restrict__ cur_out,
                                                   int2* __restrict__ csr_in,
                                                   int* __restrict__ csr_out_dst, int E) {
  int base = (blockIdx.x * 256 + threadIdx.x) * 4;
  if (base + 4 <= E) {
    int4 s4 = *(const int4*)(src + base);
    int4 d4 = *(const int4*)(dst + base);
    float4 e4 = *(const float4*)(eattr + base);
    // 8 independent atomics in flight, then the dependent stores
    int p0 = atomicAdd(&cur_in[d4.x], 1);
    int p1 = atomicAdd(&cur_in[d4.y], 1);
    int p2 = atomicAdd(&cur_in[d4.z], 1);
    int p3 = atomicAdd(&cur_in[d4.w], 1);
    int q0 = atomicAdd(&cur_out[s4.x], 1);
    int q1 = atomicAdd(&cur_out[s4.y], 1);
    int q2 = atomicAdd(&cur_out[s4.z], 1);
    int q3 = atomicAdd(&cur_out[s4.w], 1);
    csr_in[p0] = make_int2(s4.x, __float_as_int(e4.x));
    csr_in[p1] = make_int2(s4.y, __float_as_int(e4.y));
    csr_in[p2] = make_int2(s4.z, __float_as_int(e4.z));
    csr_in[p3] = make_int2(s4.w, __float_as_int(e4.w));
    csr_out_dst[q0] = d4.x;
    csr_out_dst[q1] = d4.y;
    csr_out_dst[q2] = d4.z;
    csr_out_dst[q3] = d4.w;
  } else {
    for (int i = base; i < E; i++) {
      int s = src[i], d = dst[i];
      int p = atomicAdd(&cur_in[d], 1);
      csr_in[p] = make_int2(s, __float_as_int(eattr[i]));
      int q = atomicAdd(&cur_out[s], 1);
      csr_out_dst[q] = d;
    }
  }
}

// ---------------- dual fp32 matmul: out0 = A@W0, out1 = A@W1 (A staged once) ----------------
__global__ __launch_bounds__(256) void mm128d(const float* __restrict__ A,
                                              const float* __restrict__ W0,
                                              const float* __restrict__ W1,
                                              float* __restrict__ out0,
                                              float* __restrict__ out1, int nrows) {
  __shared__ float As[64][128];   // [r][k], swizzled columns
  __shared__ float Ws[128][64];   // [k][c] for the current weight/column-half
  int r0 = blockIdx.x * 64;
  int tid = threadIdx.x;

#pragma unroll
  for (int i = 0; i < 8; i++) {
    int v = tid + 256 * i;          // float4 index into 64x128 A tile
    int r = v >> 5, k4 = (v & 31) << 2;
    int row = r0 + r;
    float4 a;
    if (row < nrows) a = *(const float4*)(A + (size_t)row * FDIM + k4);
    else a = make_float4(0.f, 0.f, 0.f, 0.f);
    int swz = ((r >> 2) & 7) << 2;
    *(float4*)(&As[r][k4 ^ swz]) = a;
  }

  int tx = tid & 15, ty = tid >> 4;
  int rbase = ty * 4;
  int swz = (ty & 7) << 2;

  for (int wsel = 0; wsel < 2; wsel++) {
    const float* W = wsel ? W1 : W0;
    float* out = wsel ? out1 : out0;
#pragma unroll
    for (int half = 0; half < 2; half++) {
      __syncthreads();  // As ready (first pass) / Ws free (later passes)
      int cb = half * 64;
#pragma unroll
      for (int i = 0; i < 8; i++) {
        int v = tid + 256 * i;      // float4 index into 128x64 W tile
        int k = v >> 4, c4 = (v & 15) << 2;
        *(float4*)(&Ws[k][c4]) = *(const float4*)(W + k * FDIM + cb + c4);
      }
      __syncthreads();

      float acc[4][4] = {};
#pragma unroll 8
      for (int k = 0; k < 128; k++) {
        int kx = k ^ swz;
        float a0 = As[rbase + 0][kx];
        float a1 = As[rbase + 1][kx];
        float a2 = As[rbase + 2][kx];
        float a3 = As[rbase + 3][kx];
        float4 w = *(float4*)(&Ws[k][tx * 4]);
        acc[0][0] += a0 * w.x; acc[0][1] += a0 * w.y; acc[0][2] += a0 * w.z; acc[0][3] += a0 * w.w;
        acc[1][0] += a1 * w.x; acc[1][1] += a1 * w.y; acc[1][2] += a1 * w.z; acc[1][3] += a1 * w.w;
        acc[2][0] += a2 * w.x; acc[2][1] += a2 * w.y; acc[2][2] += a2 * w.z; acc[2][3] += a2 * w.w;
        acc[3][0] += a3 * w.x; acc[3][1] += a3 * w.y; acc[3][2] += a3 * w.z; acc[3][3] += a3 * w.w;
      }
#pragma unroll
      for (int rr = 0; rr < 4; rr++) {
        int row = r0 + rbase + rr;
        if (row < nrows) {
          float4 o = make_float4(acc[rr][0], acc[rr][1], acc[rr][2], acc[rr][3]);
          *(float4*)(out + (size_t)row * FDIM + cb + tx * 4) = o;
        }
      }
    }
  }
}

// ---------------- GCN aggregation: float4 gather, 32 lanes/node, unroll-4 MLP ----------------
__global__ __launch_bounds__(128) void gcn_gather4(const float4* __restrict__ tin,
                                                   const float4* __restrict__ tout,
                                                   const int* __restrict__ rp_in,
                                                   const int* __restrict__ deg_in,
                                                   const int2* __restrict__ adj_in,
                                                   const int* __restrict__ rp_out,
                                                   const int* __restrict__ deg_out,
                                                   const int* __restrict__ adj_out,
                                                   const float* __restrict__ dinv_in,
                                                   const float* __restrict__ dinv_out,
                                                   const float* __restrict__ bin,
                                                   const float* __restrict__ bout,
                                                   float4* __restrict__ outp, int N) {
  int grp = threadIdx.x >> 5, lane = threadIdx.x & 31;
  int d = blockIdx.x * 4 + grp;
  if (d >= N) return;
  float wi = 0.5f * dinv_in[d], wo = 0.5f * dinv_out[d];
  float4 a0 = make_float4(0.f, 0.f, 0.f, 0.f);
  float4 a1 = a0, a2 = a0, a3 = a0;

  int p = rp_in[d], n1 = deg_in[d];
  int k = 0;
  for (; k + 4 <= n1; k += 4) {
    int s0 = adj_in[p + k].x, s1 = adj_in[p + k + 1].x, s2 = adj_in[p + k + 2].x, s3 = adj_in[p + k + 3].x;
    float w0 = wi * dinv_in[s0], w1 = wi * dinv_in[s1], w2 = wi * dinv_in[s2], w3 = wi * dinv_in[s3];
    float4 v0 = tin[(size_t)s0 * 32 + lane];
    float4 v1 = tin[(size_t)s1 * 32 + lane];
    float4 v2 = tin[(size_t)s2 * 32 + lane];
    float4 v3 = tin[(size_t)s3 * 32 + lane];
    a0.x += w0 * v0.x; a0.y += w0 * v0.y; a0.z += w0 * v0.z; a0.w += w0 * v0.w;
    a1.x += w1 * v1.x; a1.y += w1 * v1.y; a1.z += w1 * v1.z; a1.w += w1 * v1.w;
    a2.x += w2 * v2.x; a2.y += w2 * v2.y; a2.z += w2 * v2.z; a2.w += w2 * v2.w;
    a3.x += w3 * v3.x; a3.y += w3 * v3.y; a3.z += w3 * v3.z; a3.w += w3 * v3.w;
  }
  for (; k < n1; k++) {
    int s = adj_in[p + k].x;
    float w = wi * dinv_in[s];
    float4 v = tin[(size_t)s * 32 + lane];
    a0.x += w * v.x; a0.y += w * v.y; a0.z += w * v.z; a0.w += w * v.w;
  }

  int q = rp_out[d], n2 = deg_out[d];
  k = 0;
  for (; k + 4 <= n2; k += 4) {
    int s0 = adj_out[q + k], s1 = adj_out[q + k + 1], s2 = adj_out[q + k + 2], s3 = adj_out[q + k + 3];
    float w0 = wo * dinv_out[s0], w1 = wo * dinv_out[s1], w2 = wo * dinv_out[s2], w3 = wo * dinv_out[s3];
    float4 v0 = tout[(size_t)s0 * 32 + lane];
    float4 v1 = tout[(size_t)s1 * 32 + lane];
    float4 v2 = tout[(size_t)s2 * 32 + lane];
    float4 v3 = tout[(size_t)s3 * 32 + lane];
    a0.x += w0 * v0.x; a0.y += w0 * v0.y; a0.z += w0 * v0.z; a0.w += w0 * v0.w;
    a1.x += w1 * v1.x; a1.y += w1 * v1.y; a1.z += w1 * v1.z; a1.w += w1 * v1.w;
    a2.x += w2 * v2.x; a2.y += w2 * v2.y; a2.z += w2 * v2.z; a2.w += w2 * v2.w;
    a3.x += w3 * v3.x; a3.y += w3 * v3.y; a3.z += w3 * v3.z; a3.w += w3 * v3.w;
  }
  for (; k < n2; k++) {
    int s = adj_out[q + k];
    float w = wo * dinv_out[s];
    float4 v = tout[(size_t)s * 32 + lane];
    a0.x += w * v.x; a0.y += w * v.y; a0.z += w * v.z; a0.w += w * v.w;
  }

  float4 acc;
  acc.x = (a0.x + a1.x) + (a2.x + a3.x);
  acc.y = (a0.y + a1.y) + (a2.y + a3.y);
  acc.z = (a0.z + a1.z) + (a2.z + a3.z);
  acc.w = (a0.w + a1.w) + (a2.w + a3.w);

  const float4* b1 = (const float4*)bin;
  const float4* b2 = (const float4*)bout;
  float4 ba = b1[lane], bb = b2[lane];
  float4 o;
  o.x = acc.x + 0.5f * (ba.x + bb.x);
  o.y = acc.y + 0.5f * (ba.y + bb.y);
  o.z = acc.z + 0.5f * (ba.z + bb.z);
  o.w = acc.w + 0.5f * (ba.w + bb.w);
  o.x = o.x > 0.f ? o.x : 0.f;
  o.y = o.y > 0.f ? o.y : 0.f;
  o.z = o.z > 0.f ? o.z : 0.f;
  o.w = o.w > 0.f ? o.w : 0.f;
  outp[(size_t)d * 32 + lane] = o;
}

// ---------------- GATv2: fused online-softmax, 32 lanes/node, float4, unroll-2 ----------------
__global__ __launch_bounds__(128) void gat_fused2(const float4* __restrict__ gl,
                                                  const float4* __restrict__ gr,
                                                  const int* __restrict__ rp,
                                                  const int* __restrict__ deg,
                                                  const int2* __restrict__ adj,
                                                  const float* __restrict__ we,
                                                  const float* __restrict__ att,
                                                  const float* __restrict__ gatb,
                                                  float4* __restrict__ outp, int N) {
  int grp = threadIdx.x >> 5, lane = threadIdx.x & 31;
  int d = blockIdx.x * 4 + grp;
  if (d >= N) return;

  float4 grv = gr[(size_t)d * 32 + lane];
  float4 wev = ((const float4*)we)[lane];
  float4 atv = ((const float4*)att)[lane];

  int p = rp[d], n1 = deg[d];
  float m = -1e30f, den = 0.f;
  float4 o = make_float4(0.f, 0.f, 0.f, 0.f);

#define GAT_LOGIT(g4, ea, pv)                                                     \
  {                                                                               \
    float vx = g4.x + grv.x + (ea) * wev.x; vx = vx > 0.f ? vx : 0.2f * vx;       \
    float vy = g4.y + grv.y + (ea) * wev.y; vy = vy > 0.f ? vy : 0.2f * vy;       \
    float vz = g4.z + grv.z + (ea) * wev.z; vz = vz > 0.f ? vz : 0.2f * vz;       \
    float vw = g4.w + grv.w + (ea) * wev.w; vw = vw > 0.f ? vw : 0.2f * vw;       \
    pv = vx * atv.x + vy * atv.y + vz * atv.z + vw * atv.w;                       \
    pv += __shfl_xor(pv, 1);                                                      \
    pv += __shfl_xor(pv, 2);                                                      \
    pv += __shfl_xor(pv, 4);                                                      \
  }

#define GAT_UPDATE(g4, pv)                                                        \
  {                                                                               \
    float mn = fmaxf(m, pv);                                                      \
    float sc = expf(m - mn);                                                      \
    float w = expf(pv - mn);                                                      \
    den = den * sc + w;                                                           \
    o.x = o.x * sc + w * g4.x;                                                    \
    o.y = o.y * sc + w * g4.y;                                                    \
    o.z = o.z * sc + w * g4.z;                                                    \
    o.w = o.w * sc + w * g4.w;                                                    \
    m = mn;                                                                       \
  }

  int k = 0;
  for (; k + 2 <= n1; k += 2) {
    int2 e0 = adj[p + k], e1 = adj[p + k + 1];
    int s0 = e0.x, s1 = e1.x;
    float ea0 = __int_as_float(e0.y), ea1 = __int_as_float(e1.y);
    float4 g0 = gl[(size_t)s0 * 32 + lane];
    float4 g1 = gl[(size_t)s1 * 32 + lane];
    float pv0, pv1;
    GAT_LOGIT(g0, ea0, pv0);
    GAT_LOGIT(g1, ea1, pv1);
    GAT_UPDATE(g0, pv0);
    GAT_UPDATE(g1, pv1);
  }
  if (k < n1) {
    int2 e = adj[p + k];
    float ea = __int_as_float(e.y);
    float4 g = gl[(size_t)e.x * 32 + lane];
    float pv;
    GAT_LOGIT(g, ea, pv);
    GAT_UPDATE(g, pv);
  }
  {  // self loop: s = d, ea = 1.0
    float4 g = gl[(size_t)d * 32 + lane];
    float pv;
    GAT_LOGIT(g, 1.0f, pv);
    GAT_UPDATE(g, pv);
  }
#undef GAT_LOGIT
#undef GAT_UPDATE

  float4 bb = ((const float4*)gatb)[lane];
  float4 r;
  r.x = o.x / den + bb.x;
  r.y = o.y / den + bb.y;
  r.z = o.z / den + bb.z;
  r.w = o.w / den + bb.w;
  outp[(size_t)d * 32 + lane] = r;
}

// ---------------- mean pool (batch sorted: running-sum per contiguous chunk) ----------------
__global__ __launch_bounds__(128) void pool_kernel(const float* __restrict__ srcf,
                                                   const int* __restrict__ batch,
                                                   float* __restrict__ zb,
                                                   int colOff, int N) {
  __shared__ int sb[PCH];
  int c0 = blockIdx.x * PCH;
  int t = threadIdx.x;
  int nmax = N - c0; if (nmax > PCH) nmax = PCH;
  if (t < nmax) sb[t] = batch[c0 + t];
  __syncthreads();
  float run = 0.f;
  int gp = sb[0];
  for (int i = 0; i < nmax; i++) {
    int g = sb[i];
    if (g != gp) {
      atomicAdd(&zb[(size_t)gp * 256 + colOff + t], run);
      run = 0.f; gp = g;
    }
    run += srcf[(size_t)(c0 + i) * FDIM + t];
  }
  atomicAdd(&zb[(size_t)gp * 256 + colOff + t], run);
}

// ---------------- head ----------------
__global__ __launch_bounds__(128) void head_kernel(const float* __restrict__ zb,
                                                   const float* __restrict__ cnt,
                                                   const float* __restrict__ w1,
                                                   const float* __restrict__ b1,
                                                   const float* __restrict__ w2,
                                                   const float* __restrict__ b2,
                                                   float* __restrict__ out, int G) {
  __shared__ float z[256];
  __shared__ float y[128];
  int g = blockIdx.x, t = threadIdx.x;
  float c = cnt[g];
  float cm = c > 1.f ? c : 1.f;
  z[t]       = zb[(size_t)g * 256 + t] / cm;
  z[t + 128] = zb[(size_t)g * 256 + 128 + t] / cm;
  __syncthreads();
  float acc = b1[t];
  for (int k = 0; k < 256; k++) acc += z[k] * w1[k * 128 + t];
  y[t] = acc > 0.f ? acc : 0.f;
  __syncthreads();
  if (t < 2) {
    float o = b2[t];
    for (int j = 0; j < 128; j++) o += y[j] * w2[j * 2 + t];
    out[(size_t)g * 2 + t] = o;
  }
}

extern "C" void kernel_launch(void* const* d_in, const int* in_sizes, int n_in,
                              void* d_out, int out_size, void* d_ws, size_t ws_size,
                              hipStream_t stream) {
  const float* x     = (const float*)d_in[0];
  const int*   ei    = (const int*)d_in[1];
  const float* eattr = (const float*)d_in[2];
  const int*   batch = (const int*)d_in[3];
  const float* dwi   = (const float*)d_in[4];
  const float* dbi   = (const float*)d_in[5];
  const float* dwo   = (const float*)d_in[6];
  const float* dbo   = (const float*)d_in[7];
  const float* wl    = (const float*)d_in[8];
  const float* wr    = (const float*)d_in[9];
  const float* we    = (const float*)d_in[10];
  const float* att   = (const float*)d_in[11];
  const float* gatb  = (const float*)d_in[12];
  const float* w1    = (const float*)d_in[13];
  const float* b1    = (const float*)d_in[14];
  const float* w2    = (const float*)d_in[15];
  const float* b2    = (const float*)d_in[16];

  int N = in_sizes[0] / FDIM;
  int E = in_sizes[1] / 2;
  int G = out_size / 2;
  const int* src = ei;
  const int* dst = ei + E;

  // ---- workspace layout (4-byte elements; keep int2 regions 8B-aligned) ----
  float* ws = (float*)d_ws;
  size_t off = 0;
  float* A        = ws + off; off += (size_t)N * FDIM;
  float* B        = ws + off; off += (size_t)N * FDIM;
  float* C        = ws + off; off += (size_t)N * FDIM;
  float* dinv2    = ws + off; off += 2 * (size_t)N;          // [dinv_in | dinv_out]
  int* deg2       = (int*)(ws + off); off += 2 * (size_t)N;  // [deg_in | deg_out]
  int* rp_in      = (int*)(ws + off); off += (size_t)N;
  int* rp_out     = (int*)(ws + off); off += (size_t)N;
  int* cur_in     = (int*)(ws + off); off += (size_t)N;
  int* cur_out    = (int*)(ws + off); off += (size_t)N;
  int2* csr_in    = (int2*)(ws + off); off += 2 * (size_t)E; // packed {src, eattr_bits}
  int* csr_out_dst= (int*)(ws + off); off += (size_t)E;
  int* bsums      = (int*)(ws + off); off += 256;
  int* boff       = (int*)(ws + off); off += 256;
  float* zb       = ws + off; off += (size_t)G * 256;
  float* cnt      = ws + off; off += (size_t)G;

  int* deg_in = deg2, *deg_out = deg2 + N;
  float* dinv_in = dinv2, *dinv_out = dinv2 + N;

  int nb1 = cdiv(N, 1024);

  // ---- CSR build ----
  hipMemsetAsync(deg2, 0, 2 * (size_t)N * sizeof(int), stream);
  degi_kernel<<<cdiv(E, 1024), 256, 0, stream>>>(src, dst, deg_in, deg_out, E);
  dinv2_kernel<<<cdiv(2LL * N, 256), 256, 0, stream>>>(deg2, dinv2, 2 * N);
  scan1<<<nb1, 256, 0, stream>>>(deg_in, rp_in, bsums, N);
  scan2<<<1, 256, 0, stream>>>(bsums, boff, nb1);
  scan3<<<cdiv(N, 256), 256, 0, stream>>>(rp_in, boff, cur_in, N);
  scan1<<<nb1, 256, 0, stream>>>(deg_out, rp_out, bsums, N);
  scan2<<<1, 256, 0, stream>>>(bsums, boff, nb1);
  scan3<<<cdiv(N, 256), 256, 0, stream>>>(rp_out, boff, cur_out, N);
  fill_kernel<<<cdiv(E, 1024), 256, 0, stream>>>(src, dst, eattr, cur_in, cur_out,
                                                 csr_in, csr_out_dst, E);

  // ---- pool counts (binary search over sorted batch; no atomics) ----
  hipMemsetAsync(zb, 0, (size_t)G * 256 * sizeof(float), stream);
  cnt_sorted<<<cdiv(G, 256), 256, 0, stream>>>(batch, cnt, N, G);

  // ---- DirGNN layer 0 (h = x) ----
  mm128d<<<cdiv(N, 64), 256, 0, stream>>>(x, dwi, dwo, B, C, N);
  gcn_gather4<<<cdiv(N, 4), 128, 0, stream>>>((const float4*)B, (const float4*)C,
                                              rp_in, deg_in, csr_in,
                                              rp_out, deg_out, csr_out_dst,
                                              dinv_in, dinv_out, dbi, dbo, (float4*)A, N);
  // ---- DirGNN layer 1 (h = A) ----
  mm128d<<<cdiv(N, 64), 256, 0, stream>>>(A, dwi + 16384, dwo + 16384, B, C, N);
  gcn_gather4<<<cdiv(N, 4), 128, 0, stream>>>((const float4*)B, (const float4*)C,
                                              rp_in, deg_in, csr_in,
                                              rp_out, deg_out, csr_out_dst,
                                              dinv_in, dinv_out, dbi + 128, dbo + 128, (float4*)A, N);
  // pool x1 -> zb[:, 0:128]
  pool_kernel<<<cdiv(N, PCH), 128, 0, stream>>>(A, batch, zb, 0, N);

  // ---- GATv2 branch (on original x) ----
  mm128d<<<cdiv(N, 64), 256, 0, stream>>>(x, wl, wr, B, C, N);  // gl, gr
  gat_fused2<<<cdiv(N, 4), 128, 0, stream>>>((const float4*)B, (const float4*)C,
                                             rp_in, deg_in, csr_in,
                                             we, att, gatb, (float4*)A, N);
  // pool x2 -> zb[:, 128:256]
  pool_kernel<<<cdiv(N, PCH), 128, 0, stream>>>(A, batch, zb, 128, N);

  // head
  head_kernel<<<G, 128, 0, stream>>>(zb, cnt, w1, b1, w2, b2, (float*)d_out, G);
}